// Round 8
// baseline (540.180 us; speedup 1.0000x reference)
//
#include <hip/hip_runtime.h>
#include <hip/hip_bf16.h>
#include <math.h>

typedef __hip_bfloat16 bf16_t;
typedef __attribute__((ext_vector_type(8))) short short8;
typedef __attribute__((ext_vector_type(4))) float f32x4;

// Problem constants
#define L_SEQ   4096      // F*P = 16*256
#define DMODEL  1024
#define DI      2048
#define NST     16
#define DTRANK  64
#define XDBL_N  96        // DTRANK + 2*NST
#define HID     4096
#define CHUNK   32
#define NCHUNK  128       // L_SEQ / CHUNK
#define POOLED_ROWS 256   // 16 frames * 4 * 4

// ---------------------------------------------------------------------------
// async global->LDS 16B copy (global_load_lds_dwordx4)
// ---------------------------------------------------------------------------
__device__ __forceinline__ void async_load16(const void* g, void* l) {
    __builtin_amdgcn_global_load_lds(
        (const __attribute__((address_space(1))) void*)g,
        (__attribute__((address_space(3))) void*)l,
        16, 0, 0);
}

// ---------------------------------------------------------------------------
// Fused transpose+convert for remaining 5 weights (w2 handled in-GEMM).
// 128k x 64n tiles. fp32 [K,N] -> bf16 [Npad,K], pad rows zero.
//   j0 in_proj  K=1024 N=4096 Npad=4096: 512   [0,512)
//   j1 x_proj   K=2048 N=96   Npad=128 :  32   [512,544)
//   j2 dt_proj  K=64   N=2048 Npad=2048:  32   [544,576)
//   j3 out_proj K=2048 N=1024 Npad=1024: 256   [576,832)
//   j4 mlp_w1   K=1024 N=4096 Npad=4096: 512   [832,1344)
// ---------------------------------------------------------------------------
__global__ __launch_bounds__(256)
void transpose_all_kernel(const float* __restrict__ j0, bf16_t* __restrict__ o0,
                          const float* __restrict__ j1, bf16_t* __restrict__ o1,
                          const float* __restrict__ j2, bf16_t* __restrict__ o2,
                          const float* __restrict__ j3, bf16_t* __restrict__ o3,
                          const float* __restrict__ j4, bf16_t* __restrict__ o4) {
    int b = blockIdx.x;
    const float* in; bf16_t* out; int K, N, Npad, local;
    if (b < 512)        { in = j0; out = o0; K = 1024; N = 4096; Npad = 4096; local = b; }
    else if (b < 544)   { in = j1; out = o1; K = 2048; N = 96;   Npad = 128;  local = b - 512; }
    else if (b < 576)   { in = j2; out = o2; K = 64;   N = 2048; Npad = 2048; local = b - 544; }
    else if (b < 832)   { in = j3; out = o3; K = 2048; N = 1024; Npad = 1024; local = b - 576; }
    else                { in = j4; out = o4; K = 1024; N = 4096; Npad = 4096; local = b - 832; }
    int nt = Npad >> 6;
    int k0 = (local / nt) << 7, n0 = (local % nt) << 6;

    __shared__ float t[64 * 129];    // t[n][k], stride 129
    int tid = threadIdx.x;
    int kkb = tid >> 4;              // 0..15
    int nq  = (tid & 15) * 4;
#pragma unroll
    for (int it = 0; it < 8; it++) {
        int kl = it * 16 + kkb;      // 0..127
        int gk = k0 + kl, gn = n0 + nq;
        float4 v = {0.f, 0.f, 0.f, 0.f};
        if (gk < K) {
            const float* src = in + (size_t)gk * N + gn;
            if (gn + 3 < N) v = *(const float4*)src;
            else {
                if (gn + 0 < N) v.x = src[0];
                if (gn + 1 < N) v.y = src[1];
                if (gn + 2 < N) v.z = src[2];
                if (gn + 3 < N) v.w = src[3];
            }
        }
        t[(nq + 0) * 129 + kl] = v.x;
        t[(nq + 1) * 129 + kl] = v.y;
        t[(nq + 2) * 129 + kl] = v.z;
        t[(nq + 3) * 129 + kl] = v.w;
    }
    __syncthreads();
#pragma unroll
    for (int it = 0; it < 4; it++) {
        int slot = it * 256 + tid;
        int nn = slot >> 4, kc = (slot & 15) * 8;
        if (k0 + kc >= K) continue;
        const float* r = &t[nn * 129 + kc];
        short8 o;
#pragma unroll
        for (int j = 0; j < 8; j++) {
            bf16_t h = __float2bfloat16(r[j]);
            o[j] = *(short*)&h;
        }
        *(short8*)(out + (size_t)(n0 + nn) * K + k0 + kc) = o;
    }
}

// ---------------------------------------------------------------------------
// LayerNorm: one block per row, 1024 cols -> bf16
// ---------------------------------------------------------------------------
__global__ __launch_bounds__(256)
void ln_kernel(const float* __restrict__ x, const float* __restrict__ w,
               const float* __restrict__ b, bf16_t* __restrict__ out) {
    int row = blockIdx.x;
    int tid = threadIdx.x;
    const float* xr = x + (size_t)row * DMODEL;
    float v[4];
    float s = 0.f, ss = 0.f;
#pragma unroll
    for (int e = 0; e < 4; e++) {
        v[e] = xr[tid + e * 256];
        s += v[e];
        ss += v[e] * v[e];
    }
#pragma unroll
    for (int off = 32; off > 0; off >>= 1) {
        s  += __shfl_down(s, off);
        ss += __shfl_down(ss, off);
    }
    __shared__ float rs[4], rss[4];
    int wid = tid >> 6;
    if ((tid & 63) == 0) { rs[wid] = s; rss[wid] = ss; }
    __syncthreads();
    s  = rs[0] + rs[1] + rs[2] + rs[3];
    ss = rss[0] + rss[1] + rss[2] + rss[3];
    float mu  = s * (1.f / DMODEL);
    float var = ss * (1.f / DMODEL) - mu * mu;
    float inv = rsqrtf(var + 1e-5f);
#pragma unroll
    for (int e = 0; e < 4; e++) {
        int col = tid + e * 256;
        out[(size_t)row * DMODEL + col] =
            __float2bfloat16((v[e] - mu) * inv * w[col] + b[col]);
    }
}

// ---------------------------------------------------------------------------
// Fused G4-reduce(2 bf16 planes) + residual + LN2 + AvgPool(1,4,4).
// ---------------------------------------------------------------------------
__global__ __launch_bounds__(256)
void ln_pool2_kernel(const bf16_t* __restrict__ part, size_t pstride,
                     const float* __restrict__ res, const float* __restrict__ w,
                     const float* __restrict__ b, bf16_t* __restrict__ pooled) {
    int p = blockIdx.x;                  // 0..255
    int tid = threadIdx.x;
    int f = p >> 4, i4 = (p >> 2) & 3, j4 = p & 3;
    __shared__ float rs[4], rss[4];
    float acc[4] = {0.f, 0.f, 0.f, 0.f};
    float wv[4], bv[4];
#pragma unroll
    for (int e = 0; e < 4; e++) { wv[e] = w[tid + e * 256]; bv[e] = b[tid + e * 256]; }
    for (int r16 = 0; r16 < 16; r16++) {
        int ii = r16 >> 2, jj = r16 & 3;
        int row = f * 256 + (i4 * 4 + ii) * 16 + j4 * 4 + jj;
        size_t ro = (size_t)row * DMODEL;
        float v[4];
        float s = 0.f, ss = 0.f;
#pragma unroll
        for (int e = 0; e < 4; e++) {
            int col = tid + e * 256;
            float x = res[ro + col]
                    + __bfloat162float(part[ro + col])
                    + __bfloat162float(part[pstride + ro + col]);
            v[e] = x;
            s += x;
            ss += x * x;
        }
#pragma unroll
        for (int off = 32; off > 0; off >>= 1) {
            s  += __shfl_down(s, off);
            ss += __shfl_down(ss, off);
        }
        int wid = tid >> 6;
        if ((tid & 63) == 0) { rs[wid] = s; rss[wid] = ss; }
        __syncthreads();
        s  = rs[0] + rs[1] + rs[2] + rs[3];
        ss = rss[0] + rss[1] + rss[2] + rss[3];
        float mu  = s * (1.f / DMODEL);
        float var = ss * (1.f / DMODEL) - mu * mu;
        float inv = rsqrtf(var + 1e-5f);
#pragma unroll
        for (int e = 0; e < 4; e++)
            acc[e] += (v[e] - mu) * inv * wv[e] + bv[e];
        __syncthreads();
    }
#pragma unroll
    for (int e = 0; e < 4; e++)
        pooled[(size_t)p * DMODEL + tid + e * 256] = __float2bfloat16(acc[e] * (1.f / 16.f));
}

// ---------------------------------------------------------------------------
// bf16 MFMA GEMM: C[M,Nt] = epi(A[M,K] @ Bt[Nt,K]^T)
// 128x128 tile, BK=32, 256 threads (4 waves). EPI: 0 bf16; 1 bias+softplus bf16
// ---------------------------------------------------------------------------
template <int EPI>
__global__ __launch_bounds__(256, 2)
void mfma_gemm(const bf16_t* __restrict__ A, int lda,
               const bf16_t* __restrict__ Bt, int ldb,
               int K,
               float* __restrict__ Cf, bf16_t* __restrict__ Cb, int ldc,
               const float* __restrict__ bias, const float* __restrict__ res) {
    __shared__ bf16_t Asl[128 * 32];
    __shared__ bf16_t Bsl[128 * 32];
    const int tid = threadIdx.x;
    const int l = tid & 63, w = tid >> 6;
    const int m0 = blockIdx.y * 128, n0 = blockIdx.x * 128;
    const int wm = (w >> 1) * 64, wn = (w & 1) * 64;

    const int srow = tid >> 2;
    const int skc = (tid & 3) * 8;
    const bf16_t* Ag = A + (size_t)(m0 + srow) * lda + skc;
    const bf16_t* Bg = Bt + (size_t)(n0 + srow) * ldb + skc;
    bf16_t* As0 = Asl + (size_t)(w * 64) * 8;
    bf16_t* As1 = Asl + (size_t)(256 + w * 64) * 8;
    bf16_t* Bs0 = Bsl + (size_t)(w * 64) * 8;
    bf16_t* Bs1 = Bsl + (size_t)(256 + w * 64) * 8;

    f32x4 acc[4][4];
#pragma unroll
    for (int i = 0; i < 4; i++)
#pragma unroll
        for (int j = 0; j < 4; j++) acc[i][j] = (f32x4){0.f, 0.f, 0.f, 0.f};

    const short8* Asv = (const short8*)Asl;
    const short8* Bsv = (const short8*)Bsl;
    const int fr = l >> 4;
    const int fc = l & 15;

    for (int k0 = 0; k0 < K; k0 += 32) {
        __syncthreads();
        async_load16(Ag, As0);
        async_load16(Ag + (size_t)64 * lda, As1);
        async_load16(Bg, Bs0);
        async_load16(Bg + (size_t)64 * ldb, Bs1);
        Ag += 32; Bg += 32;
        __syncthreads();

        short8 a[4], b[4];
#pragma unroll
        for (int im = 0; im < 4; im++)
            a[im] = Asv[(wm + im * 16 + fc) * 4 + fr];
#pragma unroll
        for (int in = 0; in < 4; in++)
            b[in] = Bsv[(wn + in * 16 + fc) * 4 + fr];
#pragma unroll
        for (int im = 0; im < 4; im++)
#pragma unroll
            for (int in = 0; in < 4; in++)
                acc[im][in] = __builtin_amdgcn_mfma_f32_16x16x32_bf16(
                    a[im], b[in], acc[im][in], 0, 0, 0);
    }

#pragma unroll
    for (int im = 0; im < 4; im++) {
        int mbase = m0 + wm + im * 16 + fr * 4;
#pragma unroll
        for (int in = 0; in < 4; in++) {
            int n = n0 + wn + in * 16 + fc;
            float bv = (EPI == 1) ? bias[n] : 0.f;
#pragma unroll
            for (int v = 0; v < 4; v++) {
                float x = acc[im][in][v];
                size_t off = (size_t)(mbase + v) * ldc + n;
                if (EPI == 0) {
                    Cb[off] = __float2bfloat16(x);
                } else if (EPI == 1) {
                    x += bv;
                    x = (x > 20.f) ? x : log1pf(__expf(x));
                    Cb[off] = __float2bfloat16(x);
                }
            }
        }
    }
}

// ---------------------------------------------------------------------------
// Split-K variant: grid.z = K-split; partials fp32 (PBF16=0) or bf16 (PBF16=1)
// ---------------------------------------------------------------------------
template <bool PBF16>
__global__ __launch_bounds__(256, 2)
void mfma_gemm_splitk(const bf16_t* __restrict__ A, int lda,
                      const bf16_t* __restrict__ Bt, int ldb,
                      int Kper, void* __restrict__ Cpart, int ldc,
                      size_t pstride) {
    __shared__ bf16_t Asl[128 * 32];
    __shared__ bf16_t Bsl[128 * 32];
    const int tid = threadIdx.x;
    const int l = tid & 63, w = tid >> 6;
    const int m0 = blockIdx.y * 128, n0 = blockIdx.x * 128;
    const int wm = (w >> 1) * 64, wn = (w & 1) * 64;
    const int kbase = blockIdx.z * Kper;

    const int srow = tid >> 2;
    const int skc = (tid & 3) * 8;
    const bf16_t* Ag = A + (size_t)(m0 + srow) * lda + kbase + skc;
    const bf16_t* Bg = Bt + (size_t)(n0 + srow) * ldb + kbase + skc;
    bf16_t* As0 = Asl + (size_t)(w * 64) * 8;
    bf16_t* As1 = Asl + (size_t)(256 + w * 64) * 8;
    bf16_t* Bs0 = Bsl + (size_t)(w * 64) * 8;
    bf16_t* Bs1 = Bsl + (size_t)(256 + w * 64) * 8;

    f32x4 acc[4][4];
#pragma unroll
    for (int i = 0; i < 4; i++)
#pragma unroll
        for (int j = 0; j < 4; j++) acc[i][j] = (f32x4){0.f, 0.f, 0.f, 0.f};

    const short8* Asv = (const short8*)Asl;
    const short8* Bsv = (const short8*)Bsl;
    const int fr = l >> 4;
    const int fc = l & 15;

    for (int k0 = 0; k0 < Kper; k0 += 32) {
        __syncthreads();
        async_load16(Ag, As0);
        async_load16(Ag + (size_t)64 * lda, As1);
        async_load16(Bg, Bs0);
        async_load16(Bg + (size_t)64 * ldb, Bs1);
        Ag += 32; Bg += 32;
        __syncthreads();

        short8 a[4], b[4];
#pragma unroll
        for (int im = 0; im < 4; im++)
            a[im] = Asv[(wm + im * 16 + fc) * 4 + fr];
#pragma unroll
        for (int in = 0; in < 4; in++)
            b[in] = Bsv[(wn + in * 16 + fc) * 4 + fr];
#pragma unroll
        for (int im = 0; im < 4; im++)
#pragma unroll
            for (int in = 0; in < 4; in++)
                acc[im][in] = __builtin_amdgcn_mfma_f32_16x16x32_bf16(
                    a[im], b[in], acc[im][in], 0, 0, 0);
    }

#pragma unroll
    for (int im = 0; im < 4; im++) {
        int mbase = m0 + wm + im * 16 + fr * 4;
#pragma unroll
        for (int in = 0; in < 4; in++) {
            int n = n0 + wn + in * 16 + fc;
#pragma unroll
            for (int v = 0; v < 4; v++) {
                size_t o = (size_t)(mbase + v) * ldc + n;
                if (PBF16)
                    ((bf16_t*)Cpart)[(size_t)blockIdx.z * pstride + o] =
                        __float2bfloat16(acc[im][in][v]);
                else
                    ((float*)Cpart)[(size_t)blockIdx.z * pstride + o] = acc[im][in][v];
            }
        }
    }
}

// ---------------------------------------------------------------------------
// NT GEMM with fused B-transpose: C[256, N] = A[256,K]bf16 @ B[K,N]fp32.
// B read in native layout via global_load_lds; fragments built from strided
// LDS fp32 reads + cvt. grid (N/64, 1, Z), 512 threads (8 waves, 32m x 64n).
// fp32 partials to Cpart[z].
// ---------------------------------------------------------------------------
__global__ __launch_bounds__(512, 1)
void gemm_nt_kernel(const bf16_t* __restrict__ A, int lda,
                    const float* __restrict__ B, int ldb,
                    int Kper, float* __restrict__ Cpart, int ldc,
                    size_t pstride) {
    __shared__ bf16_t Asl[256 * 32];   // [m][k] bf16
    __shared__ float  Bsl[32 * 64];    // [k][n] fp32
    const int tid = threadIdx.x;
    const int l = tid & 63, w = tid >> 6;        // w 0..7
    const int n0 = blockIdx.x * 64;
    const int kbase = blockIdx.z * Kper;
    const int wm = w * 32;

    // A staging: 1024 chunks (2 rounds). chunk q = r*512+tid: row=q>>2, kc=(q&3)*8
    const int a_row = tid >> 2, a_kc = (tid & 3) * 8;
    const bf16_t* Ag = A + (size_t)a_row * lda + kbase + a_kc;
    bf16_t* As0 = Asl + (size_t)(w * 64) * 8;
    bf16_t* As1 = Asl + (size_t)(512 + w * 64) * 8;
    // B staging: 512 chunks (1 round). chunk q = tid: row=q>>4, nc=(q&15)*4
    const int b_row = tid >> 4, b_nc = (tid & 15) * 4;
    const float* Bg = B + (size_t)(kbase + b_row) * ldb + n0 + b_nc;
    float* Bs0 = Bsl + (size_t)(w * 64) * 4;

    f32x4 acc[2][4];
#pragma unroll
    for (int i = 0; i < 2; i++)
#pragma unroll
        for (int j = 0; j < 4; j++) acc[i][j] = (f32x4){0.f, 0.f, 0.f, 0.f};

    const short8* Asv = (const short8*)Asl;
    const int fr = l >> 4, fc = l & 15;

    for (int k0 = 0; k0 < Kper; k0 += 32) {
        __syncthreads();
        async_load16(Ag, As0);
        async_load16(Ag + (size_t)128 * lda, As1);
        async_load16(Bg, Bs0);
        Ag += 32;
        Bg += (size_t)32 * ldb;
        __syncthreads();

        short8 a[2], bfr[4];
        a[0] = Asv[(wm + fc) * 4 + fr];
        a[1] = Asv[(wm + 16 + fc) * 4 + fr];
#pragma unroll
        for (int j = 0; j < 4; j++) {
            const float* bp = Bsl + (size_t)(fr * 8) * 64 + j * 16 + fc;
            short8 t;
#pragma unroll
            for (int i = 0; i < 8; i++) {
                bf16_t h = __float2bfloat16(bp[i * 64]);
                t[i] = *(short*)&h;
            }
            bfr[j] = t;
        }
#pragma unroll
        for (int im = 0; im < 2; im++)
#pragma unroll
            for (int j = 0; j < 4; j++)
                acc[im][j] = __builtin_amdgcn_mfma_f32_16x16x32_bf16(
                    a[im], bfr[j], acc[im][j], 0, 0, 0);
    }

    float* Cz = Cpart + (size_t)blockIdx.z * pstride;
#pragma unroll
    for (int im = 0; im < 2; im++) {
        int mbase = wm + im * 16 + fr * 4;
#pragma unroll
        for (int j = 0; j < 4; j++) {
            int n = n0 + j * 16 + fc;
#pragma unroll
            for (int v = 0; v < 4; v++)
                Cz[(size_t)(mbase + v) * ldc + n] = acc[im][j][v];
        }
    }
}

// ---------------------------------------------------------------------------
// Split-K reduce (fp32 partials). EPI: 0 fp32+bf16; 1 bias+gelu bf16; 2 bias fp32
// ---------------------------------------------------------------------------
template <int S, int EPI>
__global__ __launch_bounds__(256)
void reduce_splitk(const float* __restrict__ part, size_t pstride, int ldp,
                   int M, int N, float* __restrict__ outf, bf16_t* __restrict__ outb,
                   int ldo, const float* __restrict__ bias) {
    int idx = blockIdx.x * 256 + threadIdx.x;
    if (idx >= M * N) return;
    int r = idx / N, c = idx - r * N;
    float s = 0.f;
#pragma unroll
    for (int z = 0; z < S; z++)
        s += part[(size_t)z * pstride + (size_t)r * ldp + c];
    size_t o = (size_t)r * ldo + c;
    if (EPI == 0) {
        outf[o] = s;
        outb[o] = __float2bfloat16(s);
    } else if (EPI == 1) {
        s += bias[c];
        s = 0.5f * s * (1.f + erff(s * 0.70710678118654752f));
        outb[o] = __float2bfloat16(s);
    } else {
        outf[o] = s + bias[c];
    }
}

// ---------------------------------------------------------------------------
// Depthwise causal conv (k=4) + bias + silu. xin = xz[:, 0:DI] (bf16, ld 2*DI)
// ---------------------------------------------------------------------------
__global__ __launch_bounds__(256)
void conv_silu_kernel(const bf16_t* __restrict__ xz, const float* __restrict__ cw,
                      const float* __restrict__ cb, bf16_t* __restrict__ u) {
    int idx = blockIdx.x * 256 + threadIdx.x;      // over L_SEQ*DI
    if (idx >= L_SEQ * DI) return;
    int ch = idx & (DI - 1);
    int l  = idx >> 11;
    float acc = cb[ch];
#pragma unroll
    for (int k = 0; k < 4; k++) {
        int ls = l - 3 + k;
        if (ls >= 0)
            acc += cw[ch * 4 + k] * __bfloat162float(xz[(size_t)ls * (2 * DI) + ch]);
    }
    u[idx] = __float2bfloat16(acc / (1.f + __expf(-acc)));
}

// ---------------------------------------------------------------------------
// Selective scan pass 1 (lane-pair split): lanes l / l+32 share one channel d,
// each holds 8 of 16 states. 256 threads = 128 channels. Grid (NCHUNK, DI/128).
// ---------------------------------------------------------------------------
__global__ __launch_bounds__(256)
void scan_pass1(const bf16_t* __restrict__ dt, const bf16_t* __restrict__ u,
                const float* __restrict__ x_dbl, const float* __restrict__ A_log,
                float* __restrict__ Pw, float* __restrict__ Sw) {
    int c = blockIdx.x;
    int tid = threadIdx.x;
    int lane = tid & 63, w = tid >> 6;
    int dloc = w * 32 + (lane & 31);
    int n0 = (lane >> 5) * 8;
    int d = blockIdx.y * 128 + dloc;
    int l0 = c * CHUNK;
    __shared__ float sB[CHUNK * NST];
    for (int i = tid; i < CHUNK * NST; i += 256)
        sB[i] = x_dbl[(size_t)(l0 + (i >> 4)) * XDBL_N + DTRANK + (i & 15)];
    __syncthreads();
    float Areg[8], h[8];
#pragma unroll
    for (int j = 0; j < 8; j++) {
        Areg[j] = -__expf(A_log[d * NST + n0 + j]);
        h[j] = 0.f;
    }
    float dts = 0.f;
    float dtl = __bfloat162float(dt[(size_t)l0 * DI + d]);
    float ul  = __bfloat162float(u[(size_t)l0 * DI + d]);
    for (int l = 0; l < CHUNK; l++) {
        float dtn = 0.f, un = 0.f;
        if (l + 1 < CHUNK) {
            int gl = l0 + l + 1;
            dtn = __bfloat162float(dt[(size_t)gl * DI + d]);
            un  = __bfloat162float(u[(size_t)gl * DI + d]);
        }
        float du = dtl * ul;
        dts += dtl;
#pragma unroll
        for (int j = 0; j < 8; j++) {
            float a = __expf(dtl * Areg[j]);
            h[j] = a * h[j] + du * sB[l * NST + n0 + j];
        }
        dtl = dtn; ul = un;
    }
    size_t base = ((size_t)c * DI + d) * NST + n0;
#pragma unroll
    for (int j = 0; j < 8; j++) {
        Pw[base + j] = __expf(dts * Areg[j]);
        Sw[base + j] = h[j];
    }
}

// ---------------------------------------------------------------------------
// Selective scan pass 2: sequential prefix over chunks; init in-place over Sw.
// ---------------------------------------------------------------------------
__global__ __launch_bounds__(256)
void scan_pass2(const float* __restrict__ Pw, float* __restrict__ SwInit) {
    int tid = blockIdx.x * 256 + threadIdx.x;   // 0 .. DI*NST-1
    if (tid >= DI * NST) return;
    const int DN = DI * NST;
    size_t idx = tid;
    float h = 0.f;
    float p = Pw[idx], s = SwInit[idx];
    for (int c = 0; c < NCHUNK; c++) {
        size_t nidx = idx + DN;
        float pn = 0.f, sn = 0.f;
        if (c + 1 < NCHUNK) { pn = Pw[nidx]; sn = SwInit[nidx]; }
        SwInit[idx] = h;                 // becomes init state for chunk c
        h = p * h + s;
        p = pn; s = sn; idx = nidx;
    }
}

// ---------------------------------------------------------------------------
// Selective scan pass 3 (lane-pair split): replay with init,
// yy = (h.C + u*D) * silu(z); y halves combined via shfl_xor(32).
// ---------------------------------------------------------------------------
__global__ __launch_bounds__(256)
void scan_pass3(const bf16_t* __restrict__ dt, const bf16_t* __restrict__ u,
                const float* __restrict__ x_dbl, const float* __restrict__ A_log,
                const float* __restrict__ Dp, const float* __restrict__ initw,
                const bf16_t* __restrict__ xz, bf16_t* __restrict__ yy) {
    int c = blockIdx.x;
    int tid = threadIdx.x;
    int lane = tid & 63, w = tid >> 6;
    int dloc = w * 32 + (lane & 31);
    int n0 = (lane >> 5) * 8;
    int d = blockIdx.y * 128 + dloc;
    int l0 = c * CHUNK;
    __shared__ float sBC[CHUNK * 2 * NST];
    for (int i = tid; i < CHUNK * 2 * NST; i += 256)
        sBC[i] = x_dbl[(size_t)(l0 + (i >> 5)) * XDBL_N + DTRANK + (i & 31)];
    __syncthreads();
    float Areg[8], h[8];
    size_t base = ((size_t)c * DI + d) * NST + n0;
#pragma unroll
    for (int j = 0; j < 8; j++) {
        Areg[j] = -__expf(A_log[d * NST + n0 + j]);
        h[j] = initw[base + j];
    }
    float Dd = Dp[d];
    float dtl = __bfloat162float(dt[(size_t)l0 * DI + d]);
    float ul  = __bfloat162float(u[(size_t)l0 * DI + d]);
    float zv  = __bfloat162float(xz[(size_t)l0 * (2 * DI) + DI + d]);
    for (int l = 0; l < CHUNK; l++) {
        float dtn = 0.f, un = 0.f, zn = 0.f;
        if (l + 1 < CHUNK) {
            int gl = l0 + l + 1;
            dtn = __bfloat162float(dt[(size_t)gl * DI + d]);
            un  = __bfloat162float(u[(size_t)gl * DI + d]);
            zn  = __bfloat162float(xz[(size_t)gl * (2 * DI) + DI + d]);
        }
        float du = dtl * ul;
        float y = 0.f;
#pragma unroll
        for (int j = 0; j < 8; j++) {
            float a = __expf(dtl * Areg[j]);
            h[j] = a * h[j] + du * sBC[l * 32 + n0 + j];
            y += h[j] * sBC[l * 32 + NST + n0 + j];
        }
        y += __shfl_xor(y, 32);
        float sz = zv / (1.f + __expf(-zv));
        if ((lane >> 5) == 0)
            yy[(size_t)(l0 + l) * DI + d] = __float2bfloat16((y + ul * Dd) * sz);
        dtl = dtn; ul = un; zv = zn;
    }
}

// ---------------------------------------------------------------------------
extern "C" void kernel_launch(void* const* d_in, const int* in_sizes, int n_in,
                              void* d_out, int out_size, void* d_ws, size_t ws_size,
                              hipStream_t stream) {
    const float* vst        = (const float*)d_in[0];
    const float* ln_w       = (const float*)d_in[1];
    const float* ln_b       = (const float*)d_in[2];
    const float* in_proj_w  = (const float*)d_in[3];
    const float* conv_w     = (const float*)d_in[4];
    const float* conv_b     = (const float*)d_in[5];
    const float* x_proj_w   = (const float*)d_in[6];
    const float* dt_proj_w  = (const float*)d_in[7];
    const float* dt_proj_b  = (const float*)d_in[8];
    const float* A_log      = (const float*)d_in[9];
    const float* D_param    = (const float*)d_in[10];
    const float* out_proj_w = (const float*)d_in[11];
    const float* fln_w      = (const float*)d_in[12];
    const float* fln_b      = (const float*)d_in[13];
    const float* mlp_w1     = (const float*)d_in[14];
    const float* mlp_b1     = (const float*)d_in[15];
    const float* mlp_w2     = (const float*)d_in[16];
    const float* mlp_b2     = (const float*)d_in[17];
    float* out = (float*)d_out;

    // ---------------- workspace layout ----------------
    char* wsb = (char*)d_ws;
    size_t off = 0;
    auto alloc_bf = [&](size_t n) { bf16_t* p = (bf16_t*)(wsb + off); off += n * 2; return p; };
    auto alloc_f  = [&](size_t n) { float*  p = (float*)(wsb + off); off += n * 4; return p; };

    // bf16 transposed weights (w2 NOT transposed - handled by gemm_nt)
    bf16_t* w1t  = alloc_bf((size_t)(2 * DI) * DMODEL);   // [4096,1024]
    bf16_t* xpt  = alloc_bf((size_t)128 * DI);            // [128,2048] (96 padded)
    bf16_t* dtpt = alloc_bf((size_t)DI * DTRANK);         // [2048,64]
    bf16_t* opt  = alloc_bf((size_t)DMODEL * DI);         // [1024,2048]
    bf16_t* m1t  = alloc_bf((size_t)HID * DMODEL);        // [4096,1024]
    // activations
    bf16_t* xz_bf   = alloc_bf((size_t)L_SEQ * 2 * DI);   // 33.5 MB
    bf16_t* u_bf    = alloc_bf((size_t)L_SEQ * DI);       // 16.8 MB
    bf16_t* dt_bf   = alloc_bf((size_t)L_SEQ * DI);       // 16.8 MB
    bf16_t* xdbl_bf = alloc_bf((size_t)L_SEQ * XDBL_N);
    bf16_t* yy_bf   = alloc_bf((size_t)L_SEQ * DI);       // 16.8 MB
    float*  xdbl_f  = alloc_f((size_t)L_SEQ * XDBL_N);
    float*  Pw      = alloc_f((size_t)NCHUNK * DI * NST); // 16.8 MB
    float*  Sw      = alloc_f((size_t)NCHUNK * DI * NST); // 16.8 MB (also init, in-place)
    // aliases over dead regions
    bf16_t* xn_bf   = yy_bf;           // LN1 out; dead before pass3 writes yy
    float*  g2part  = Pw;              // [8][4096][128] fp32 = 16.8 MB, dead before pass1
    bf16_t* g4part  = xz_bf;           // [2][4096][1024] bf16 = 16.8 MB, xz dead after pass3
    bf16_t* pooled  = dt_bf;           // dt dead after pass3
    bf16_t* h1_bf   = dt_bf + (size_t)POOLED_ROWS * DMODEL;
    float*  g5part  = (float*)yy_bf;   // [4][256][4096] fp32 = 16.8 MB, yy dead after G4
    float*  g6part  = (float*)xz_bf;   // [8][256][4096] fp32 = 33.5 MB, g4part dead after pool

    dim3 blk256(256);

    // 0) weight transposes (w2 excluded), one dispatch (1344 tiles)
    transpose_all_kernel<<<1344, blk256, 0, stream>>>(
        in_proj_w, w1t, x_proj_w, xpt, dt_proj_w, dtpt,
        out_proj_w, opt, mlp_w1, m1t);

    // 1) LN1: vst -> xn_bf
    ln_kernel<<<L_SEQ, blk256, 0, stream>>>(vst, ln_w, ln_b, xn_bf);

    // 2) G1: xz = xn @ in_proj  -> bf16 [L,4096]
    mfma_gemm<0><<<dim3((2 * DI) / 128, L_SEQ / 128), blk256, 0, stream>>>(
        xn_bf, DMODEL, w1t, DMODEL, DMODEL, nullptr, xz_bf, 2 * DI, nullptr, nullptr);

    // 3) conv+silu: xz[:,:DI] -> u_bf
    conv_silu_kernel<<<(L_SEQ * DI) / 256, blk256, 0, stream>>>(xz_bf, conv_w, conv_b, u_bf);

    // 4) G2 split-K(8): x_dbl = u @ x_proj  [4096,2048]x[2048,96->128]
    mfma_gemm_splitk<false><<<dim3(1, L_SEQ / 128, 8), blk256, 0, stream>>>(
        u_bf, DI, xpt, DI, DI / 8, g2part, 128, (size_t)L_SEQ * 128);
    reduce_splitk<8, 0><<<(L_SEQ * XDBL_N) / 256, blk256, 0, stream>>>(
        g2part, (size_t)L_SEQ * 128, 128, L_SEQ, XDBL_N, xdbl_f, xdbl_bf, XDBL_N, nullptr);

    // 5) G3: dt = softplus(x_dbl[:,:64] @ dt_proj + b) -> bf16 [L,2048]
    mfma_gemm<1><<<dim3(DI / 128, L_SEQ / 128), blk256, 0, stream>>>(
        xdbl_bf, XDBL_N, dtpt, DTRANK, DTRANK, nullptr, dt_bf, DI, dt_proj_b, nullptr);

    // 6-8) chunked selective scan (CHUNK=32, lane-pair split: 32 waves/CU)
    scan_pass1<<<dim3(NCHUNK, DI / 128), blk256, 0, stream>>>(
        dt_bf, u_bf, xdbl_f, A_log, Pw, Sw);
    scan_pass2<<<(DI * NST) / 256, blk256, 0, stream>>>(Pw, Sw);
    scan_pass3<<<dim3(NCHUNK, DI / 128), blk256, 0, stream>>>(
        dt_bf, u_bf, xdbl_f, A_log, D_param, Sw, xz_bf, yy_bf);

    // 9) G4 split-K(2), bf16 partials: yy @ out_proj (residual folded into pool)
    mfma_gemm_splitk<true><<<dim3(DMODEL / 128, L_SEQ / 128, 2), blk256, 0, stream>>>(
        yy_bf, DI, opt, DI, DI / 2, g4part, DMODEL, (size_t)L_SEQ * DMODEL);

    // 10) fused G4-reduce + residual + LN2 + avgpool -> pooled bf16 [256,1024]
    ln_pool2_kernel<<<POOLED_ROWS, blk256, 0, stream>>>(
        g4part, (size_t)L_SEQ * DMODEL, vst, fln_w, fln_b, pooled);

    // 12) G5 split-K(4): h1 = gelu(pooled @ mlp_w1 + b1) -> bf16 [256,4096]
    mfma_gemm_splitk<false><<<dim3(HID / 128, POOLED_ROWS / 128, 4), blk256, 0, stream>>>(
        pooled, DMODEL, m1t, DMODEL, DMODEL / 4, g5part, HID, (size_t)POOLED_ROWS * HID);
    reduce_splitk<4, 1><<<(POOLED_ROWS * HID) / 256, blk256, 0, stream>>>(
        g5part, (size_t)POOLED_ROWS * HID, HID, POOLED_ROWS, HID, nullptr, h1_bf, HID, mlp_b1);

    // 13) G6: out = h1 @ mlp_w2(native fp32) + b2 via NT kernel, split-K(8)
    gemm_nt_kernel<<<dim3(HID / 64, 1, 8), dim3(512), 0, stream>>>(
        h1_bf, HID, mlp_w2, HID, HID / 8, g6part, HID, (size_t)POOLED_ROWS * HID);
    reduce_splitk<8, 2><<<(POOLED_ROWS * HID) / 256, blk256, 0, stream>>>(
        g6part, (size_t)POOLED_ROWS * HID, HID, POOLED_ROWS, HID, out, nullptr, HID, mlp_b2);
}

// Round 9
// 472.801 us; speedup vs baseline: 1.1425x; 1.1425x over previous
//
#include <hip/hip_runtime.h>
#include <hip/hip_bf16.h>
#include <math.h>

typedef __hip_bfloat16 bf16_t;
typedef __attribute__((ext_vector_type(8))) short short8;
typedef __attribute__((ext_vector_type(4))) float f32x4;

// Problem constants
#define L_SEQ   4096      // F*P = 16*256
#define DMODEL  1024
#define DI      2048
#define NST     16
#define DTRANK  64
#define XDBL_N  96        // DTRANK + 2*NST
#define HID     4096
#define CHUNK   32
#define NCHUNK  128       // L_SEQ / CHUNK
#define POOLED_ROWS 256   // 16 frames * 4 * 4

// ---------------------------------------------------------------------------
// async global->LDS 16B copy (global_load_lds_dwordx4)
// ---------------------------------------------------------------------------
__device__ __forceinline__ void async_load16(const bf16_t* g, bf16_t* l) {
    __builtin_amdgcn_global_load_lds(
        (const __attribute__((address_space(1))) void*)g,
        (__attribute__((address_space(3))) void*)l,
        16, 0, 0);
}

// branchless stable softplus with fast intrinsics (bf16-output accuracy)
__device__ __forceinline__ float softplus_f(float x) {
    return fmaxf(x, 0.f) + __logf(1.f + __expf(-fabsf(x)));
}

// ---------------------------------------------------------------------------
// Fused transpose+convert for all 6 weights. 128k x 64n tiles.
// fp32 [K,N] row-major -> bf16 [Npad,K] row-major, pad rows zero.
//   j0 in_proj  K=1024 N=4096 Npad=4096: 512   [0,512)
//   j1 x_proj   K=2048 N=96   Npad=128 :  32   [512,544)
//   j2 dt_proj  K=64   N=2048 Npad=2048:  32   [544,576)
//   j3 out_proj K=2048 N=1024 Npad=1024: 256   [576,832)
//   j4 mlp_w1   K=1024 N=4096 Npad=4096: 512   [832,1344)
//   j5 mlp_w2   K=4096 N=4096 Npad=4096: 2048  [1344,3392)
// ---------------------------------------------------------------------------
__global__ __launch_bounds__(256)
void transpose_all_kernel(const float* __restrict__ j0, bf16_t* __restrict__ o0,
                          const float* __restrict__ j1, bf16_t* __restrict__ o1,
                          const float* __restrict__ j2, bf16_t* __restrict__ o2,
                          const float* __restrict__ j3, bf16_t* __restrict__ o3,
                          const float* __restrict__ j4, bf16_t* __restrict__ o4,
                          const float* __restrict__ j5, bf16_t* __restrict__ o5) {
    int b = blockIdx.x;
    const float* in; bf16_t* out; int K, N, Npad, local;
    if (b < 512)        { in = j0; out = o0; K = 1024; N = 4096; Npad = 4096; local = b; }
    else if (b < 544)   { in = j1; out = o1; K = 2048; N = 96;   Npad = 128;  local = b - 512; }
    else if (b < 576)   { in = j2; out = o2; K = 64;   N = 2048; Npad = 2048; local = b - 544; }
    else if (b < 832)   { in = j3; out = o3; K = 2048; N = 1024; Npad = 1024; local = b - 576; }
    else if (b < 1344)  { in = j4; out = o4; K = 1024; N = 4096; Npad = 4096; local = b - 832; }
    else                { in = j5; out = o5; K = 4096; N = 4096; Npad = 4096; local = b - 1344; }
    int nt = Npad >> 6;
    int k0 = (local / nt) << 7, n0 = (local % nt) << 6;

    __shared__ float t[64 * 129];    // t[n][k], stride 129
    int tid = threadIdx.x;
    int kkb = tid >> 4;              // 0..15
    int nq  = (tid & 15) * 4;
#pragma unroll
    for (int it = 0; it < 8; it++) {
        int kl = it * 16 + kkb;      // 0..127
        int gk = k0 + kl, gn = n0 + nq;
        float4 v = {0.f, 0.f, 0.f, 0.f};
        if (gk < K) {
            const float* src = in + (size_t)gk * N + gn;
            if (gn + 3 < N) v = *(const float4*)src;
            else {
                if (gn + 0 < N) v.x = src[0];
                if (gn + 1 < N) v.y = src[1];
                if (gn + 2 < N) v.z = src[2];
                if (gn + 3 < N) v.w = src[3];
            }
        }
        t[(nq + 0) * 129 + kl] = v.x;
        t[(nq + 1) * 129 + kl] = v.y;
        t[(nq + 2) * 129 + kl] = v.z;
        t[(nq + 3) * 129 + kl] = v.w;
    }
    __syncthreads();
#pragma unroll
    for (int it = 0; it < 4; it++) {
        int slot = it * 256 + tid;
        int nn = slot >> 4, kc = (slot & 15) * 8;
        if (k0 + kc >= K) continue;
        const float* r = &t[nn * 129 + kc];
        short8 o;
#pragma unroll
        for (int j = 0; j < 8; j++) {
            bf16_t h = __float2bfloat16(r[j]);
            o[j] = *(short*)&h;
        }
        *(short8*)(out + (size_t)(n0 + nn) * K + k0 + kc) = o;
    }
}

// ---------------------------------------------------------------------------
// LayerNorm: one block per row, 1024 cols -> bf16
// ---------------------------------------------------------------------------
__global__ __launch_bounds__(256)
void ln_kernel(const float* __restrict__ x, const float* __restrict__ w,
               const float* __restrict__ b, bf16_t* __restrict__ out) {
    int row = blockIdx.x;
    int tid = threadIdx.x;
    const float* xr = x + (size_t)row * DMODEL;
    float v[4];
    float s = 0.f, ss = 0.f;
#pragma unroll
    for (int e = 0; e < 4; e++) {
        v[e] = xr[tid + e * 256];
        s += v[e];
        ss += v[e] * v[e];
    }
#pragma unroll
    for (int off = 32; off > 0; off >>= 1) {
        s  += __shfl_down(s, off);
        ss += __shfl_down(ss, off);
    }
    __shared__ float rs[4], rss[4];
    int wid = tid >> 6;
    if ((tid & 63) == 0) { rs[wid] = s; rss[wid] = ss; }
    __syncthreads();
    s  = rs[0] + rs[1] + rs[2] + rs[3];
    ss = rss[0] + rss[1] + rss[2] + rss[3];
    float mu  = s * (1.f / DMODEL);
    float var = ss * (1.f / DMODEL) - mu * mu;
    float inv = rsqrtf(var + 1e-5f);
#pragma unroll
    for (int e = 0; e < 4; e++) {
        int col = tid + e * 256;
        out[(size_t)row * DMODEL + col] =
            __float2bfloat16((v[e] - mu) * inv * w[col] + b[col]);
    }
}

// ---------------------------------------------------------------------------
// Fused G4-reduce(2 bf16 planes) + residual + LN2 + AvgPool(1,4,4).
// ---------------------------------------------------------------------------
__global__ __launch_bounds__(256)
void ln_pool2_kernel(const bf16_t* __restrict__ part, size_t pstride,
                     const float* __restrict__ res, const float* __restrict__ w,
                     const float* __restrict__ b, bf16_t* __restrict__ pooled) {
    int p = blockIdx.x;                  // 0..255
    int tid = threadIdx.x;
    int f = p >> 4, i4 = (p >> 2) & 3, j4 = p & 3;
    __shared__ float rs[4], rss[4];
    float acc[4] = {0.f, 0.f, 0.f, 0.f};
    float wv[4], bv[4];
#pragma unroll
    for (int e = 0; e < 4; e++) { wv[e] = w[tid + e * 256]; bv[e] = b[tid + e * 256]; }
    for (int r16 = 0; r16 < 16; r16++) {
        int ii = r16 >> 2, jj = r16 & 3;
        int row = f * 256 + (i4 * 4 + ii) * 16 + j4 * 4 + jj;
        size_t ro = (size_t)row * DMODEL;
        float v[4];
        float s = 0.f, ss = 0.f;
#pragma unroll
        for (int e = 0; e < 4; e++) {
            int col = tid + e * 256;
            float x = res[ro + col]
                    + __bfloat162float(part[ro + col])
                    + __bfloat162float(part[pstride + ro + col]);
            v[e] = x;
            s += x;
            ss += x * x;
        }
#pragma unroll
        for (int off = 32; off > 0; off >>= 1) {
            s  += __shfl_down(s, off);
            ss += __shfl_down(ss, off);
        }
        int wid = tid >> 6;
        if ((tid & 63) == 0) { rs[wid] = s; rss[wid] = ss; }
        __syncthreads();
        s  = rs[0] + rs[1] + rs[2] + rs[3];
        ss = rss[0] + rss[1] + rss[2] + rss[3];
        float mu  = s * (1.f / DMODEL);
        float var = ss * (1.f / DMODEL) - mu * mu;
        float inv = rsqrtf(var + 1e-5f);
#pragma unroll
        for (int e = 0; e < 4; e++)
            acc[e] += (v[e] - mu) * inv * wv[e] + bv[e];
        __syncthreads();
    }
#pragma unroll
    for (int e = 0; e < 4; e++)
        pooled[(size_t)p * DMODEL + tid + e * 256] = __float2bfloat16(acc[e] * (1.f / 16.f));
}

// ---------------------------------------------------------------------------
// bf16 MFMA GEMM: C[M,Nt] = epi(A[M,K] @ Bt[Nt,K]^T)
// 128x128 tile, BK=32, 256 threads (4 waves). EPI: 0 bf16; 1 bias+softplus bf16
// ---------------------------------------------------------------------------
template <int EPI>
__global__ __launch_bounds__(256, 2)
void mfma_gemm(const bf16_t* __restrict__ A, int lda,
               const bf16_t* __restrict__ Bt, int ldb,
               int K,
               float* __restrict__ Cf, bf16_t* __restrict__ Cb, int ldc,
               const float* __restrict__ bias, const float* __restrict__ res) {
    __shared__ bf16_t Asl[128 * 32];
    __shared__ bf16_t Bsl[128 * 32];
    const int tid = threadIdx.x;
    const int l = tid & 63, w = tid >> 6;
    const int m0 = blockIdx.y * 128, n0 = blockIdx.x * 128;
    const int wm = (w >> 1) * 64, wn = (w & 1) * 64;

    const int srow = tid >> 2;
    const int skc = (tid & 3) * 8;
    const bf16_t* Ag = A + (size_t)(m0 + srow) * lda + skc;
    const bf16_t* Bg = Bt + (size_t)(n0 + srow) * ldb + skc;
    bf16_t* As0 = Asl + (size_t)(w * 64) * 8;
    bf16_t* As1 = Asl + (size_t)(256 + w * 64) * 8;
    bf16_t* Bs0 = Bsl + (size_t)(w * 64) * 8;
    bf16_t* Bs1 = Bsl + (size_t)(256 + w * 64) * 8;

    f32x4 acc[4][4];
#pragma unroll
    for (int i = 0; i < 4; i++)
#pragma unroll
        for (int j = 0; j < 4; j++) acc[i][j] = (f32x4){0.f, 0.f, 0.f, 0.f};

    const short8* Asv = (const short8*)Asl;
    const short8* Bsv = (const short8*)Bsl;
    const int fr = l >> 4;
    const int fc = l & 15;

    for (int k0 = 0; k0 < K; k0 += 32) {
        __syncthreads();
        async_load16(Ag, As0);
        async_load16(Ag + (size_t)64 * lda, As1);
        async_load16(Bg, Bs0);
        async_load16(Bg + (size_t)64 * ldb, Bs1);
        Ag += 32; Bg += 32;
        __syncthreads();

        short8 a[4], b[4];
#pragma unroll
        for (int im = 0; im < 4; im++)
            a[im] = Asv[(wm + im * 16 + fc) * 4 + fr];
#pragma unroll
        for (int in = 0; in < 4; in++)
            b[in] = Bsv[(wn + in * 16 + fc) * 4 + fr];
#pragma unroll
        for (int im = 0; im < 4; im++)
#pragma unroll
            for (int in = 0; in < 4; in++)
                acc[im][in] = __builtin_amdgcn_mfma_f32_16x16x32_bf16(
                    a[im], b[in], acc[im][in], 0, 0, 0);
    }

#pragma unroll
    for (int im = 0; im < 4; im++) {
        int mbase = m0 + wm + im * 16 + fr * 4;
#pragma unroll
        for (int in = 0; in < 4; in++) {
            int n = n0 + wn + in * 16 + fc;
            float bv = (EPI == 1) ? bias[n] : 0.f;
#pragma unroll
            for (int v = 0; v < 4; v++) {
                float x = acc[im][in][v];
                size_t off = (size_t)(mbase + v) * ldc + n;
                if (EPI == 0) {
                    Cb[off] = __float2bfloat16(x);
                } else if (EPI == 1) {
                    Cb[off] = __float2bfloat16(softplus_f(x + bv));
                }
            }
        }
    }
}

// ---------------------------------------------------------------------------
// Split-K variant: grid.z = K-split; partials fp32 (PBF16=0) or bf16 (PBF16=1)
// ---------------------------------------------------------------------------
template <bool PBF16>
__global__ __launch_bounds__(256, 2)
void mfma_gemm_splitk(const bf16_t* __restrict__ A, int lda,
                      const bf16_t* __restrict__ Bt, int ldb,
                      int Kper, void* __restrict__ Cpart, int ldc,
                      size_t pstride) {
    __shared__ bf16_t Asl[128 * 32];
    __shared__ bf16_t Bsl[128 * 32];
    const int tid = threadIdx.x;
    const int l = tid & 63, w = tid >> 6;
    const int m0 = blockIdx.y * 128, n0 = blockIdx.x * 128;
    const int wm = (w >> 1) * 64, wn = (w & 1) * 64;
    const int kbase = blockIdx.z * Kper;

    const int srow = tid >> 2;
    const int skc = (tid & 3) * 8;
    const bf16_t* Ag = A + (size_t)(m0 + srow) * lda + kbase + skc;
    const bf16_t* Bg = Bt + (size_t)(n0 + srow) * ldb + kbase + skc;
    bf16_t* As0 = Asl + (size_t)(w * 64) * 8;
    bf16_t* As1 = Asl + (size_t)(256 + w * 64) * 8;
    bf16_t* Bs0 = Bsl + (size_t)(w * 64) * 8;
    bf16_t* Bs1 = Bsl + (size_t)(256 + w * 64) * 8;

    f32x4 acc[4][4];
#pragma unroll
    for (int i = 0; i < 4; i++)
#pragma unroll
        for (int j = 0; j < 4; j++) acc[i][j] = (f32x4){0.f, 0.f, 0.f, 0.f};

    const short8* Asv = (const short8*)Asl;
    const short8* Bsv = (const short8*)Bsl;
    const int fr = l >> 4;
    const int fc = l & 15;

    for (int k0 = 0; k0 < Kper; k0 += 32) {
        __syncthreads();
        async_load16(Ag, As0);
        async_load16(Ag + (size_t)64 * lda, As1);
        async_load16(Bg, Bs0);
        async_load16(Bg + (size_t)64 * ldb, Bs1);
        Ag += 32; Bg += 32;
        __syncthreads();

        short8 a[4], b[4];
#pragma unroll
        for (int im = 0; im < 4; im++)
            a[im] = Asv[(wm + im * 16 + fc) * 4 + fr];
#pragma unroll
        for (int in = 0; in < 4; in++)
            b[in] = Bsv[(wn + in * 16 + fc) * 4 + fr];
#pragma unroll
        for (int im = 0; im < 4; im++)
#pragma unroll
            for (int in = 0; in < 4; in++)
                acc[im][in] = __builtin_amdgcn_mfma_f32_16x16x32_bf16(
                    a[im], b[in], acc[im][in], 0, 0, 0);
    }

#pragma unroll
    for (int im = 0; im < 4; im++) {
        int mbase = m0 + wm + im * 16 + fr * 4;
#pragma unroll
        for (int in = 0; in < 4; in++) {
            int n = n0 + wn + in * 16 + fc;
#pragma unroll
            for (int v = 0; v < 4; v++) {
                size_t o = (size_t)(mbase + v) * ldc + n;
                if (PBF16)
                    ((bf16_t*)Cpart)[(size_t)blockIdx.z * pstride + o] =
                        __float2bfloat16(acc[im][in][v]);
                else
                    ((float*)Cpart)[(size_t)blockIdx.z * pstride + o] = acc[im][in][v];
            }
        }
    }
}

// ---------------------------------------------------------------------------
// Split-K reduce (fp32 partials). EPI: 0 fp32+bf16; 1 bias+gelu bf16; 2 bias fp32
// ---------------------------------------------------------------------------
template <int S, int EPI>
__global__ __launch_bounds__(256)
void reduce_splitk(const float* __restrict__ part, size_t pstride, int ldp,
                   int M, int N, float* __restrict__ outf, bf16_t* __restrict__ outb,
                   int ldo, const float* __restrict__ bias) {
    int idx = blockIdx.x * 256 + threadIdx.x;
    if (idx >= M * N) return;
    int r = idx / N, c = idx - r * N;
    float s = 0.f;
#pragma unroll
    for (int z = 0; z < S; z++)
        s += part[(size_t)z * pstride + (size_t)r * ldp + c];
    size_t o = (size_t)r * ldo + c;
    if (EPI == 0) {
        outf[o] = s;
        outb[o] = __float2bfloat16(s);
    } else if (EPI == 1) {
        s += bias[c];
        s = 0.5f * s * (1.f + erff(s * 0.70710678118654752f));
        outb[o] = __float2bfloat16(s);
    } else {
        outf[o] = s + bias[c];
    }
}

// ---------------------------------------------------------------------------
// Depthwise causal conv (k=4) + bias + silu. xin = xz[:, 0:DI] (bf16, ld 2*DI)
// ---------------------------------------------------------------------------
__global__ __launch_bounds__(256)
void conv_silu_kernel(const bf16_t* __restrict__ xz, const float* __restrict__ cw,
                      const float* __restrict__ cb, bf16_t* __restrict__ u) {
    int idx = blockIdx.x * 256 + threadIdx.x;      // over L_SEQ*DI
    if (idx >= L_SEQ * DI) return;
    int ch = idx & (DI - 1);
    int l  = idx >> 11;
    float acc = cb[ch];
#pragma unroll
    for (int k = 0; k < 4; k++) {
        int ls = l - 3 + k;
        if (ls >= 0)
            acc += cw[ch * 4 + k] * __bfloat162float(xz[(size_t)ls * (2 * DI) + ch]);
    }
    u[idx] = __float2bfloat16(acc / (1.f + __expf(-acc)));
}

// ---------------------------------------------------------------------------
// Selective scan pass 1 (lane-pair split): lanes l / l+32 share one channel d,
// each holds 8 of 16 states. 256 threads = 128 channels. Grid (NCHUNK, DI/128).
// Writes S (state from h=0) and dtsum[c][d] (P recomputed in pass2).
// ---------------------------------------------------------------------------
__global__ __launch_bounds__(256)
void scan_pass1(const bf16_t* __restrict__ dt, const bf16_t* __restrict__ u,
                const float* __restrict__ x_dbl, const float* __restrict__ A_log,
                float* __restrict__ dtsum, float* __restrict__ Sw) {
    int c = blockIdx.x;
    int tid = threadIdx.x;
    int lane = tid & 63, w = tid >> 6;
    int dloc = w * 32 + (lane & 31);
    int n0 = (lane >> 5) * 8;
    int d = blockIdx.y * 128 + dloc;
    int l0 = c * CHUNK;
    __shared__ float sB[CHUNK * NST];
    for (int i = tid; i < CHUNK * NST; i += 256)
        sB[i] = x_dbl[(size_t)(l0 + (i >> 4)) * XDBL_N + DTRANK + (i & 15)];
    __syncthreads();
    float Areg[8], h[8];
#pragma unroll
    for (int j = 0; j < 8; j++) {
        Areg[j] = -__expf(A_log[d * NST + n0 + j]);
        h[j] = 0.f;
    }
    float dts = 0.f;
    float dtl = __bfloat162float(dt[(size_t)l0 * DI + d]);
    float ul  = __bfloat162float(u[(size_t)l0 * DI + d]);
    for (int l = 0; l < CHUNK; l++) {
        float dtn = 0.f, un = 0.f;
        if (l + 1 < CHUNK) {
            int gl = l0 + l + 1;
            dtn = __bfloat162float(dt[(size_t)gl * DI + d]);
            un  = __bfloat162float(u[(size_t)gl * DI + d]);
        }
        float du = dtl * ul;
        dts += dtl;
#pragma unroll
        for (int j = 0; j < 8; j++) {
            float a = __expf(dtl * Areg[j]);
            h[j] = a * h[j] + du * sB[l * NST + n0 + j];
        }
        dtl = dtn; ul = un;
    }
    size_t base = ((size_t)c * DI + d) * NST + n0;
#pragma unroll
    for (int j = 0; j < 8; j++)
        Sw[base + j] = h[j];
    if (n0 == 0)
        dtsum[(size_t)c * DI + d] = dts;
}

// ---------------------------------------------------------------------------
// Selective scan pass 2: sequential prefix over chunks; init in-place over Sw.
// P recomputed from dtsum + A_log (identical exp math as before).
// thread tid = d*NST + n.
// ---------------------------------------------------------------------------
__global__ __launch_bounds__(256)
void scan_pass2(const float* __restrict__ dtsum, const float* __restrict__ A_log,
                float* __restrict__ SwInit) {
    int tid = blockIdx.x * 256 + threadIdx.x;   // 0 .. DI*NST-1
    if (tid >= DI * NST) return;
    int d = tid >> 4;
    float A = -__expf(A_log[tid]);              // A_log[d][n] flat = tid
    const int DN = DI * NST;
    size_t idx = tid;
    float h = 0.f;
    float ds = dtsum[d], s = SwInit[idx];
    for (int c = 0; c < NCHUNK; c++) {
        size_t nidx = idx + DN;
        float dsn = 0.f, sn = 0.f;
        if (c + 1 < NCHUNK) {
            dsn = dtsum[(size_t)(c + 1) * DI + d];
            sn  = SwInit[nidx];
        }
        float p = __expf(ds * A);
        SwInit[idx] = h;                 // becomes init state for chunk c
        h = p * h + s;
        ds = dsn; s = sn; idx = nidx;
    }
}

// ---------------------------------------------------------------------------
// Selective scan pass 3 (lane-pair split): replay with init,
// yy = (h.C + u*D) * silu(z); y halves combined via shfl_xor(32).
// ---------------------------------------------------------------------------
__global__ __launch_bounds__(256)
void scan_pass3(const bf16_t* __restrict__ dt, const bf16_t* __restrict__ u,
                const float* __restrict__ x_dbl, const float* __restrict__ A_log,
                const float* __restrict__ Dp, const float* __restrict__ initw,
                const bf16_t* __restrict__ xz, bf16_t* __restrict__ yy) {
    int c = blockIdx.x;
    int tid = threadIdx.x;
    int lane = tid & 63, w = tid >> 6;
    int dloc = w * 32 + (lane & 31);
    int n0 = (lane >> 5) * 8;
    int d = blockIdx.y * 128 + dloc;
    int l0 = c * CHUNK;
    __shared__ float sBC[CHUNK * 2 * NST];
    for (int i = tid; i < CHUNK * 2 * NST; i += 256)
        sBC[i] = x_dbl[(size_t)(l0 + (i >> 5)) * XDBL_N + DTRANK + (i & 31)];
    __syncthreads();
    float Areg[8], h[8];
    size_t base = ((size_t)c * DI + d) * NST + n0;
#pragma unroll
    for (int j = 0; j < 8; j++) {
        Areg[j] = -__expf(A_log[d * NST + n0 + j]);
        h[j] = initw[base + j];
    }
    float Dd = Dp[d];
    float dtl = __bfloat162float(dt[(size_t)l0 * DI + d]);
    float ul  = __bfloat162float(u[(size_t)l0 * DI + d]);
    float zv  = __bfloat162float(xz[(size_t)l0 * (2 * DI) + DI + d]);
    for (int l = 0; l < CHUNK; l++) {
        float dtn = 0.f, un = 0.f, zn = 0.f;
        if (l + 1 < CHUNK) {
            int gl = l0 + l + 1;
            dtn = __bfloat162float(dt[(size_t)gl * DI + d]);
            un  = __bfloat162float(u[(size_t)gl * DI + d]);
            zn  = __bfloat162float(xz[(size_t)gl * (2 * DI) + DI + d]);
        }
        float du = dtl * ul;
        float y = 0.f;
#pragma unroll
        for (int j = 0; j < 8; j++) {
            float a = __expf(dtl * Areg[j]);
            h[j] = a * h[j] + du * sBC[l * 32 + n0 + j];
            y += h[j] * sBC[l * 32 + NST + n0 + j];
        }
        y += __shfl_xor(y, 32);
        float sz = zv / (1.f + __expf(-zv));
        if ((lane >> 5) == 0)
            yy[(size_t)(l0 + l) * DI + d] = __float2bfloat16((y + ul * Dd) * sz);
        dtl = dtn; ul = un; zv = zn;
    }
}

// ---------------------------------------------------------------------------
extern "C" void kernel_launch(void* const* d_in, const int* in_sizes, int n_in,
                              void* d_out, int out_size, void* d_ws, size_t ws_size,
                              hipStream_t stream) {
    const float* vst        = (const float*)d_in[0];
    const float* ln_w       = (const float*)d_in[1];
    const float* ln_b       = (const float*)d_in[2];
    const float* in_proj_w  = (const float*)d_in[3];
    const float* conv_w     = (const float*)d_in[4];
    const float* conv_b     = (const float*)d_in[5];
    const float* x_proj_w   = (const float*)d_in[6];
    const float* dt_proj_w  = (const float*)d_in[7];
    const float* dt_proj_b  = (const float*)d_in[8];
    const float* A_log      = (const float*)d_in[9];
    const float* D_param    = (const float*)d_in[10];
    const float* out_proj_w = (const float*)d_in[11];
    const float* fln_w      = (const float*)d_in[12];
    const float* fln_b      = (const float*)d_in[13];
    const float* mlp_w1     = (const float*)d_in[14];
    const float* mlp_b1     = (const float*)d_in[15];
    const float* mlp_w2     = (const float*)d_in[16];
    const float* mlp_b2     = (const float*)d_in[17];
    float* out = (float*)d_out;

    // ---------------- workspace layout (round-7 order preserved) ----------------
    char* wsb = (char*)d_ws;
    size_t off = 0;
    auto alloc_bf = [&](size_t n) { bf16_t* p = (bf16_t*)(wsb + off); off += n * 2; return p; };
    auto alloc_f  = [&](size_t n) { float*  p = (float*)(wsb + off); off += n * 4; return p; };

    // bf16 transposed weights
    bf16_t* w1t  = alloc_bf((size_t)(2 * DI) * DMODEL);   // [4096,1024]
    bf16_t* xpt  = alloc_bf((size_t)128 * DI);            // [128,2048] (96 padded)
    bf16_t* dtpt = alloc_bf((size_t)DI * DTRANK);         // [2048,64]
    bf16_t* opt  = alloc_bf((size_t)DMODEL * DI);         // [1024,2048]
    bf16_t* m1t  = alloc_bf((size_t)HID * DMODEL);        // [4096,1024]
    bf16_t* m2t  = alloc_bf((size_t)HID * HID);           // [4096,4096]
    // activations
    bf16_t* xz_bf   = alloc_bf((size_t)L_SEQ * 2 * DI);   // 33.5 MB
    bf16_t* u_bf    = alloc_bf((size_t)L_SEQ * DI);       // 16.8 MB
    bf16_t* dt_bf   = alloc_bf((size_t)L_SEQ * DI);       // 16.8 MB
    bf16_t* xdbl_bf = alloc_bf((size_t)L_SEQ * XDBL_N);
    bf16_t* yy_bf   = alloc_bf((size_t)L_SEQ * DI);       // 16.8 MB
    float*  xdbl_f  = alloc_f((size_t)L_SEQ * XDBL_N);
    float*  Pw      = alloc_f((size_t)NCHUNK * DI * NST); // 16.8 MB (g2part / dtsum)
    float*  Sw      = alloc_f((size_t)NCHUNK * DI * NST); // 16.8 MB (S + init, in-place)
    // aliases over dead regions
    bf16_t* xn_bf   = yy_bf;           // LN1 out; dead before pass3 writes yy
    float*  g2part  = Pw;              // [8][4096][128] fp32, dead before pass1
    float*  dtsum   = Pw;              // [128][2048] fp32 = 1 MB, written by pass1
    bf16_t* g4part  = xz_bf;           // [2][4096][1024] bf16, xz dead after pass3
    bf16_t* pooled  = dt_bf;           // dt dead after pass3
    bf16_t* h1_bf   = dt_bf + (size_t)POOLED_ROWS * DMODEL;
    float*  g5part  = (float*)yy_bf;   // [4][256][4096] fp32, yy dead after G4
    float*  g6part  = (float*)xz_bf;   // [8][256][4096] fp32, g4part dead after pool

    dim3 blk256(256);

    // 0) all weight transposes, one dispatch (3392 128x64 tiles)
    transpose_all_kernel<<<3392, blk256, 0, stream>>>(
        in_proj_w, w1t, x_proj_w, xpt, dt_proj_w, dtpt,
        out_proj_w, opt, mlp_w1, m1t, mlp_w2, m2t);

    // 1) LN1: vst -> xn_bf
    ln_kernel<<<L_SEQ, blk256, 0, stream>>>(vst, ln_w, ln_b, xn_bf);

    // 2) G1: xz = xn @ in_proj  -> bf16 [L,4096]
    mfma_gemm<0><<<dim3((2 * DI) / 128, L_SEQ / 128), blk256, 0, stream>>>(
        xn_bf, DMODEL, w1t, DMODEL, DMODEL, nullptr, xz_bf, 2 * DI, nullptr, nullptr);

    // 3) conv+silu: xz[:,:DI] -> u_bf
    conv_silu_kernel<<<(L_SEQ * DI) / 256, blk256, 0, stream>>>(xz_bf, conv_w, conv_b, u_bf);

    // 4) G2 split-K(8): x_dbl = u @ x_proj  [4096,2048]x[2048,96->128]
    mfma_gemm_splitk<false><<<dim3(1, L_SEQ / 128, 8), blk256, 0, stream>>>(
        u_bf, DI, xpt, DI, DI / 8, g2part, 128, (size_t)L_SEQ * 128);
    reduce_splitk<8, 0><<<(L_SEQ * XDBL_N) / 256, blk256, 0, stream>>>(
        g2part, (size_t)L_SEQ * 128, 128, L_SEQ, XDBL_N, xdbl_f, xdbl_bf, XDBL_N, nullptr);

    // 5) G3: dt = softplus(x_dbl[:,:64] @ dt_proj + b) -> bf16 [L,2048]
    mfma_gemm<1><<<dim3(DI / 128, L_SEQ / 128), blk256, 0, stream>>>(
        xdbl_bf, XDBL_N, dtpt, DTRANK, DTRANK, nullptr, dt_bf, DI, dt_proj_b, nullptr);

    // 6-8) chunked selective scan (CHUNK=32, lane-pair split: 32 waves/CU)
    scan_pass1<<<dim3(NCHUNK, DI / 128), blk256, 0, stream>>>(
        dt_bf, u_bf, xdbl_f, A_log, dtsum, Sw);
    scan_pass2<<<(DI * NST) / 256, blk256, 0, stream>>>(dtsum, A_log, Sw);
    scan_pass3<<<dim3(NCHUNK, DI / 128), blk256, 0, stream>>>(
        dt_bf, u_bf, xdbl_f, A_log, D_param, Sw, xz_bf, yy_bf);

    // 9) G4 split-K(2), bf16 partials: yy @ out_proj (residual folded into pool)
    mfma_gemm_splitk<true><<<dim3(DMODEL / 128, L_SEQ / 128, 2), blk256, 0, stream>>>(
        yy_bf, DI, opt, DI, DI / 2, g4part, DMODEL, (size_t)L_SEQ * DMODEL);

    // 10) fused G4-reduce + residual + LN2 + avgpool -> pooled bf16 [256,1024]
    ln_pool2_kernel<<<POOLED_ROWS, blk256, 0, stream>>>(
        g4part, (size_t)L_SEQ * DMODEL, vst, fln_w, fln_b, pooled);

    // 12) G5 split-K(4): h1 = gelu(pooled @ mlp_w1 + b1) -> bf16 [256,4096]
    mfma_gemm_splitk<false><<<dim3(HID / 128, POOLED_ROWS / 128, 4), blk256, 0, stream>>>(
        pooled, DMODEL, m1t, DMODEL, DMODEL / 4, g5part, HID, (size_t)POOLED_ROWS * HID);
    reduce_splitk<4, 1><<<(POOLED_ROWS * HID) / 256, blk256, 0, stream>>>(
        g5part, (size_t)POOLED_ROWS * HID, HID, POOLED_ROWS, HID, nullptr, h1_bf, HID, mlp_b1);

    // 13) G6 split-K(8): out = h1 @ mlp_w2 + b2 -> fp32 [256,4096]
    mfma_gemm_splitk<false><<<dim3(HID / 128, POOLED_ROWS / 128, 8), blk256, 0, stream>>>(
        h1_bf, HID, m2t, HID, HID / 8, g6part, HID, (size_t)POOLED_ROWS * HID);
    reduce_splitk<8, 2><<<(POOLED_ROWS * HID) / 256, blk256, 0, stream>>>(
        g6part, (size_t)POOLED_ROWS * HID, HID, POOLED_ROWS, HID, out, nullptr, HID, mlp_b2);
}

// Round 10
// 450.199 us; speedup vs baseline: 1.1999x; 1.0502x over previous
//
#include <hip/hip_runtime.h>
#include <hip/hip_bf16.h>
#include <math.h>

typedef __hip_bfloat16 bf16_t;
typedef __attribute__((ext_vector_type(8))) short short8;
typedef __attribute__((ext_vector_type(4))) float f32x4;

// Problem constants
#define L_SEQ   4096      // F*P = 16*256
#define DMODEL  1024
#define DI      2048
#define NST     16
#define DTRANK  64
#define XDBL_N  96        // DTRANK + 2*NST
#define HID     4096
#define CHUNK   32
#define NCHUNK  128       // L_SEQ / CHUNK
#define POOLED_ROWS 256   // 16 frames * 4 * 4

// ---------------------------------------------------------------------------
// async global->LDS 16B copy (global_load_lds_dwordx4)
// ---------------------------------------------------------------------------
__device__ __forceinline__ void async_load16(const bf16_t* g, bf16_t* l) {
    __builtin_amdgcn_global_load_lds(
        (const __attribute__((address_space(1))) void*)g,
        (__attribute__((address_space(3))) void*)l,
        16, 0, 0);
}
__device__ __forceinline__ void async_load16f(const float* g, float* l) {
    __builtin_amdgcn_global_load_lds(
        (const __attribute__((address_space(1))) void*)g,
        (__attribute__((address_space(3))) void*)l,
        16, 0, 0);
}

// branchless stable softplus with fast intrinsics (bf16-output accuracy)
__device__ __forceinline__ float softplus_f(float x) {
    return fmaxf(x, 0.f) + __logf(1.f + __expf(-fabsf(x)));
}

// ---------------------------------------------------------------------------
// Fused transpose+convert for 5 weights (w2 consumed natively by gemm_nt).
// 128k x 64n tiles. fp32 [K,N] row-major -> bf16 [Npad,K], pad rows zero.
//   j0 in_proj  K=1024 N=4096 Npad=4096: 512   [0,512)
//   j1 x_proj   K=2048 N=96   Npad=128 :  32   [512,544)
//   j2 dt_proj  K=64   N=2048 Npad=2048:  32   [544,576)
//   j3 out_proj K=2048 N=1024 Npad=1024: 256   [576,832)
//   j4 mlp_w1   K=1024 N=4096 Npad=4096: 512   [832,1344)
// ---------------------------------------------------------------------------
__global__ __launch_bounds__(256)
void transpose_all_kernel(const float* __restrict__ j0, bf16_t* __restrict__ o0,
                          const float* __restrict__ j1, bf16_t* __restrict__ o1,
                          const float* __restrict__ j2, bf16_t* __restrict__ o2,
                          const float* __restrict__ j3, bf16_t* __restrict__ o3,
                          const float* __restrict__ j4, bf16_t* __restrict__ o4) {
    int b = blockIdx.x;
    const float* in; bf16_t* out; int K, N, Npad, local;
    if (b < 512)        { in = j0; out = o0; K = 1024; N = 4096; Npad = 4096; local = b; }
    else if (b < 544)   { in = j1; out = o1; K = 2048; N = 96;   Npad = 128;  local = b - 512; }
    else if (b < 576)   { in = j2; out = o2; K = 64;   N = 2048; Npad = 2048; local = b - 544; }
    else if (b < 832)   { in = j3; out = o3; K = 2048; N = 1024; Npad = 1024; local = b - 576; }
    else                { in = j4; out = o4; K = 1024; N = 4096; Npad = 4096; local = b - 832; }
    int nt = Npad >> 6;
    int k0 = (local / nt) << 7, n0 = (local % nt) << 6;

    __shared__ float t[64 * 129];    // t[n][k], stride 129
    int tid = threadIdx.x;
    int kkb = tid >> 4;              // 0..15
    int nq  = (tid & 15) * 4;
#pragma unroll
    for (int it = 0; it < 8; it++) {
        int kl = it * 16 + kkb;      // 0..127
        int gk = k0 + kl, gn = n0 + nq;
        float4 v = {0.f, 0.f, 0.f, 0.f};
        if (gk < K) {
            const float* src = in + (size_t)gk * N + gn;
            if (gn + 3 < N) v = *(const float4*)src;
            else {
                if (gn + 0 < N) v.x = src[0];
                if (gn + 1 < N) v.y = src[1];
                if (gn + 2 < N) v.z = src[2];
                if (gn + 3 < N) v.w = src[3];
            }
        }
        t[(nq + 0) * 129 + kl] = v.x;
        t[(nq + 1) * 129 + kl] = v.y;
        t[(nq + 2) * 129 + kl] = v.z;
        t[(nq + 3) * 129 + kl] = v.w;
    }
    __syncthreads();
#pragma unroll
    for (int it = 0; it < 4; it++) {
        int slot = it * 256 + tid;
        int nn = slot >> 4, kc = (slot & 15) * 8;
        if (k0 + kc >= K) continue;
        const float* r = &t[nn * 129 + kc];
        short8 o;
#pragma unroll
        for (int j = 0; j < 8; j++) {
            bf16_t h = __float2bfloat16(r[j]);
            o[j] = *(short*)&h;
        }
        *(short8*)(out + (size_t)(n0 + nn) * K + k0 + kc) = o;
    }
}

// ---------------------------------------------------------------------------
// LayerNorm: one block per row, 1024 cols -> bf16
// ---------------------------------------------------------------------------
__global__ __launch_bounds__(256)
void ln_kernel(const float* __restrict__ x, const float* __restrict__ w,
               const float* __restrict__ b, bf16_t* __restrict__ out) {
    int row = blockIdx.x;
    int tid = threadIdx.x;
    const float* xr = x + (size_t)row * DMODEL;
    float v[4];
    float s = 0.f, ss = 0.f;
#pragma unroll
    for (int e = 0; e < 4; e++) {
        v[e] = xr[tid + e * 256];
        s += v[e];
        ss += v[e] * v[e];
    }
#pragma unroll
    for (int off = 32; off > 0; off >>= 1) {
        s  += __shfl_down(s, off);
        ss += __shfl_down(ss, off);
    }
    __shared__ float rs[4], rss[4];
    int wid = tid >> 6;
    if ((tid & 63) == 0) { rs[wid] = s; rss[wid] = ss; }
    __syncthreads();
    s  = rs[0] + rs[1] + rs[2] + rs[3];
    ss = rss[0] + rss[1] + rss[2] + rss[3];
    float mu  = s * (1.f / DMODEL);
    float var = ss * (1.f / DMODEL) - mu * mu;
    float inv = rsqrtf(var + 1e-5f);
#pragma unroll
    for (int e = 0; e < 4; e++) {
        int col = tid + e * 256;
        out[(size_t)row * DMODEL + col] =
            __float2bfloat16((v[e] - mu) * inv * w[col] + b[col]);
    }
}

// ---------------------------------------------------------------------------
// Fused G4-reduce(2 bf16 planes) + residual + LN2 + AvgPool(1,4,4).
// ---------------------------------------------------------------------------
__global__ __launch_bounds__(256)
void ln_pool2_kernel(const bf16_t* __restrict__ part, size_t pstride,
                     const float* __restrict__ res, const float* __restrict__ w,
                     const float* __restrict__ b, bf16_t* __restrict__ pooled) {
    int p = blockIdx.x;                  // 0..255
    int tid = threadIdx.x;
    int f = p >> 4, i4 = (p >> 2) & 3, j4 = p & 3;
    __shared__ float rs[4], rss[4];
    float acc[4] = {0.f, 0.f, 0.f, 0.f};
    float wv[4], bv[4];
#pragma unroll
    for (int e = 0; e < 4; e++) { wv[e] = w[tid + e * 256]; bv[e] = b[tid + e * 256]; }
    for (int r16 = 0; r16 < 16; r16++) {
        int ii = r16 >> 2, jj = r16 & 3;
        int row = f * 256 + (i4 * 4 + ii) * 16 + j4 * 4 + jj;
        size_t ro = (size_t)row * DMODEL;
        float v[4];
        float s = 0.f, ss = 0.f;
#pragma unroll
        for (int e = 0; e < 4; e++) {
            int col = tid + e * 256;
            float x = res[ro + col]
                    + __bfloat162float(part[ro + col])
                    + __bfloat162float(part[pstride + ro + col]);
            v[e] = x;
            s += x;
            ss += x * x;
        }
#pragma unroll
        for (int off = 32; off > 0; off >>= 1) {
            s  += __shfl_down(s, off);
            ss += __shfl_down(ss, off);
        }
        int wid = tid >> 6;
        if ((tid & 63) == 0) { rs[wid] = s; rss[wid] = ss; }
        __syncthreads();
        s  = rs[0] + rs[1] + rs[2] + rs[3];
        ss = rss[0] + rss[1] + rss[2] + rss[3];
        float mu  = s * (1.f / DMODEL);
        float var = ss * (1.f / DMODEL) - mu * mu;
        float inv = rsqrtf(var + 1e-5f);
#pragma unroll
        for (int e = 0; e < 4; e++)
            acc[e] += (v[e] - mu) * inv * wv[e] + bv[e];
        __syncthreads();
    }
#pragma unroll
    for (int e = 0; e < 4; e++)
        pooled[(size_t)p * DMODEL + tid + e * 256] = __float2bfloat16(acc[e] * (1.f / 16.f));
}

// ---------------------------------------------------------------------------
// bf16 MFMA GEMM: C[M,Nt] = epi(A[M,K] @ Bt[Nt,K]^T)
// 128x128 tile, BK=32, 256 threads (4 waves). EPI: 0 bf16; 1 bias+softplus bf16
// ---------------------------------------------------------------------------
template <int EPI>
__global__ __launch_bounds__(256, 2)
void mfma_gemm(const bf16_t* __restrict__ A, int lda,
               const bf16_t* __restrict__ Bt, int ldb,
               int K,
               float* __restrict__ Cf, bf16_t* __restrict__ Cb, int ldc,
               const float* __restrict__ bias, const float* __restrict__ res) {
    __shared__ bf16_t Asl[128 * 32];
    __shared__ bf16_t Bsl[128 * 32];
    const int tid = threadIdx.x;
    const int l = tid & 63, w = tid >> 6;
    const int m0 = blockIdx.y * 128, n0 = blockIdx.x * 128;
    const int wm = (w >> 1) * 64, wn = (w & 1) * 64;

    const int srow = tid >> 2;
    const int skc = (tid & 3) * 8;
    const bf16_t* Ag = A + (size_t)(m0 + srow) * lda + skc;
    const bf16_t* Bg = Bt + (size_t)(n0 + srow) * ldb + skc;
    bf16_t* As0 = Asl + (size_t)(w * 64) * 8;
    bf16_t* As1 = Asl + (size_t)(256 + w * 64) * 8;
    bf16_t* Bs0 = Bsl + (size_t)(w * 64) * 8;
    bf16_t* Bs1 = Bsl + (size_t)(256 + w * 64) * 8;

    f32x4 acc[4][4];
#pragma unroll
    for (int i = 0; i < 4; i++)
#pragma unroll
        for (int j = 0; j < 4; j++) acc[i][j] = (f32x4){0.f, 0.f, 0.f, 0.f};

    const short8* Asv = (const short8*)Asl;
    const short8* Bsv = (const short8*)Bsl;
    const int fr = l >> 4;
    const int fc = l & 15;

    for (int k0 = 0; k0 < K; k0 += 32) {
        __syncthreads();
        async_load16(Ag, As0);
        async_load16(Ag + (size_t)64 * lda, As1);
        async_load16(Bg, Bs0);
        async_load16(Bg + (size_t)64 * ldb, Bs1);
        Ag += 32; Bg += 32;
        __syncthreads();

        short8 a[4], b[4];
#pragma unroll
        for (int im = 0; im < 4; im++)
            a[im] = Asv[(wm + im * 16 + fc) * 4 + fr];
#pragma unroll
        for (int in = 0; in < 4; in++)
            b[in] = Bsv[(wn + in * 16 + fc) * 4 + fr];
#pragma unroll
        for (int im = 0; im < 4; im++)
#pragma unroll
            for (int in = 0; in < 4; in++)
                acc[im][in] = __builtin_amdgcn_mfma_f32_16x16x32_bf16(
                    a[im], b[in], acc[im][in], 0, 0, 0);
    }

#pragma unroll
    for (int im = 0; im < 4; im++) {
        int mbase = m0 + wm + im * 16 + fr * 4;
#pragma unroll
        for (int in = 0; in < 4; in++) {
            int n = n0 + wn + in * 16 + fc;
            float bv = (EPI == 1) ? bias[n] : 0.f;
#pragma unroll
            for (int v = 0; v < 4; v++) {
                float x = acc[im][in][v];
                size_t off = (size_t)(mbase + v) * ldc + n;
                if (EPI == 0) {
                    Cb[off] = __float2bfloat16(x);
                } else if (EPI == 1) {
                    Cb[off] = __float2bfloat16(softplus_f(x + bv));
                }
            }
        }
    }
}

// ---------------------------------------------------------------------------
// Split-K variant: grid.z = K-split; partials fp32 (PBF16=0) or bf16 (PBF16=1)
// ---------------------------------------------------------------------------
template <bool PBF16>
__global__ __launch_bounds__(256, 2)
void mfma_gemm_splitk(const bf16_t* __restrict__ A, int lda,
                      const bf16_t* __restrict__ Bt, int ldb,
                      int Kper, void* __restrict__ Cpart, int ldc,
                      size_t pstride) {
    __shared__ bf16_t Asl[128 * 32];
    __shared__ bf16_t Bsl[128 * 32];
    const int tid = threadIdx.x;
    const int l = tid & 63, w = tid >> 6;
    const int m0 = blockIdx.y * 128, n0 = blockIdx.x * 128;
    const int wm = (w >> 1) * 64, wn = (w & 1) * 64;
    const int kbase = blockIdx.z * Kper;

    const int srow = tid >> 2;
    const int skc = (tid & 3) * 8;
    const bf16_t* Ag = A + (size_t)(m0 + srow) * lda + kbase + skc;
    const bf16_t* Bg = Bt + (size_t)(n0 + srow) * ldb + kbase + skc;
    bf16_t* As0 = Asl + (size_t)(w * 64) * 8;
    bf16_t* As1 = Asl + (size_t)(256 + w * 64) * 8;
    bf16_t* Bs0 = Bsl + (size_t)(w * 64) * 8;
    bf16_t* Bs1 = Bsl + (size_t)(256 + w * 64) * 8;

    f32x4 acc[4][4];
#pragma unroll
    for (int i = 0; i < 4; i++)
#pragma unroll
        for (int j = 0; j < 4; j++) acc[i][j] = (f32x4){0.f, 0.f, 0.f, 0.f};

    const short8* Asv = (const short8*)Asl;
    const short8* Bsv = (const short8*)Bsl;
    const int fr = l >> 4;
    const int fc = l & 15;

    for (int k0 = 0; k0 < Kper; k0 += 32) {
        __syncthreads();
        async_load16(Ag, As0);
        async_load16(Ag + (size_t)64 * lda, As1);
        async_load16(Bg, Bs0);
        async_load16(Bg + (size_t)64 * ldb, Bs1);
        Ag += 32; Bg += 32;
        __syncthreads();

        short8 a[4], b[4];
#pragma unroll
        for (int im = 0; im < 4; im++)
            a[im] = Asv[(wm + im * 16 + fc) * 4 + fr];
#pragma unroll
        for (int in = 0; in < 4; in++)
            b[in] = Bsv[(wn + in * 16 + fc) * 4 + fr];
#pragma unroll
        for (int im = 0; im < 4; im++)
#pragma unroll
            for (int in = 0; in < 4; in++)
                acc[im][in] = __builtin_amdgcn_mfma_f32_16x16x32_bf16(
                    a[im], b[in], acc[im][in], 0, 0, 0);
    }

#pragma unroll
    for (int im = 0; im < 4; im++) {
        int mbase = m0 + wm + im * 16 + fr * 4;
#pragma unroll
        for (int in = 0; in < 4; in++) {
            int n = n0 + wn + in * 16 + fc;
#pragma unroll
            for (int v = 0; v < 4; v++) {
                size_t o = (size_t)(mbase + v) * ldc + n;
                if (PBF16)
                    ((bf16_t*)Cpart)[(size_t)blockIdx.z * pstride + o] =
                        __float2bfloat16(acc[im][in][v]);
                else
                    ((float*)Cpart)[(size_t)blockIdx.z * pstride + o] = acc[im][in][v];
            }
        }
    }
}

// ---------------------------------------------------------------------------
// NT GEMM with fused B-convert: C[256,N] = A[256,K]bf16 @ B[K,N]fp32.
// B staged natively (coalesced) via global_load_lds; fragments via strided
// LDS fp32 reads + cvt (4-way bank alias, acceptable). 512 thr (8 waves,
// 32m x 64n each), grid (N/64, 1, Z). fp32 partials.
// ---------------------------------------------------------------------------
__global__ __launch_bounds__(512, 1)
void gemm_nt_kernel(const bf16_t* __restrict__ A, int lda,
                    const float* __restrict__ B, int ldb,
                    int Kper, float* __restrict__ Cpart, int ldc,
                    size_t pstride) {
    __shared__ bf16_t Asl[256 * 32];   // [m][k] bf16
    __shared__ float  Bsl[32 * 64];    // [k][n] fp32
    const int tid = threadIdx.x;
    const int l = tid & 63, w = tid >> 6;        // w 0..7
    const int n0 = blockIdx.x * 64;
    const int kbase = blockIdx.z * Kper;
    const int wm = w * 32;

    const int a_row = tid >> 2, a_kc = (tid & 3) * 8;
    const bf16_t* Ag = A + (size_t)a_row * lda + kbase + a_kc;
    bf16_t* As0 = Asl + (size_t)(w * 64) * 8;
    bf16_t* As1 = Asl + (size_t)(512 + w * 64) * 8;
    const int b_row = tid >> 4, b_nc = (tid & 15) * 4;
    const float* Bg = B + (size_t)(kbase + b_row) * ldb + n0 + b_nc;
    float* Bs0 = Bsl + (size_t)(w * 64) * 4;

    f32x4 acc[2][4];
#pragma unroll
    for (int i = 0; i < 2; i++)
#pragma unroll
        for (int j = 0; j < 4; j++) acc[i][j] = (f32x4){0.f, 0.f, 0.f, 0.f};

    const short8* Asv = (const short8*)Asl;
    const int fr = l >> 4, fc = l & 15;

    for (int k0 = 0; k0 < Kper; k0 += 32) {
        __syncthreads();
        async_load16(Ag, As0);
        async_load16(Ag + (size_t)128 * lda, As1);
        async_load16f(Bg, Bs0);
        Ag += 32;
        Bg += (size_t)32 * ldb;
        __syncthreads();

        short8 a[2], bfr[4];
        a[0] = Asv[(wm + fc) * 4 + fr];
        a[1] = Asv[(wm + 16 + fc) * 4 + fr];
#pragma unroll
        for (int j = 0; j < 4; j++) {
            const float* bp = Bsl + (size_t)(fr * 8) * 64 + j * 16 + fc;
            short8 t;
#pragma unroll
            for (int i = 0; i < 8; i++) {
                bf16_t h = __float2bfloat16(bp[i * 64]);
                t[i] = *(short*)&h;
            }
            bfr[j] = t;
        }
#pragma unroll
        for (int im = 0; im < 2; im++)
#pragma unroll
            for (int j = 0; j < 4; j++)
                acc[im][j] = __builtin_amdgcn_mfma_f32_16x16x32_bf16(
                    a[im], bfr[j], acc[im][j], 0, 0, 0);
    }

    float* Cz = Cpart + (size_t)blockIdx.z * pstride;
#pragma unroll
    for (int im = 0; im < 2; im++) {
        int mbase = wm + im * 16 + fr * 4;
#pragma unroll
        for (int j = 0; j < 4; j++) {
            int n = n0 + j * 16 + fc;
#pragma unroll
            for (int v = 0; v < 4; v++)
                Cz[(size_t)(mbase + v) * ldc + n] = acc[im][j][v];
        }
    }
}

// ---------------------------------------------------------------------------
// Split-K reduce (fp32 partials). EPI: 0 fp32+bf16; 1 bias+gelu bf16; 2 bias fp32
// ---------------------------------------------------------------------------
template <int S, int EPI>
__global__ __launch_bounds__(256)
void reduce_splitk(const float* __restrict__ part, size_t pstride, int ldp,
                   int M, int N, float* __restrict__ outf, bf16_t* __restrict__ outb,
                   int ldo, const float* __restrict__ bias) {
    int idx = blockIdx.x * 256 + threadIdx.x;
    if (idx >= M * N) return;
    int r = idx / N, c = idx - r * N;
    float s = 0.f;
#pragma unroll
    for (int z = 0; z < S; z++)
        s += part[(size_t)z * pstride + (size_t)r * ldp + c];
    size_t o = (size_t)r * ldo + c;
    if (EPI == 0) {
        outf[o] = s;
        outb[o] = __float2bfloat16(s);
    } else if (EPI == 1) {
        s += bias[c];
        s = 0.5f * s * (1.f + erff(s * 0.70710678118654752f));
        outb[o] = __float2bfloat16(s);
    } else {
        outf[o] = s + bias[c];
    }
}

// ---------------------------------------------------------------------------
// Depthwise causal conv (k=4) + bias + silu, channel-pair vectorized.
// ---------------------------------------------------------------------------
__global__ __launch_bounds__(256)
void conv_silu_kernel(const bf16_t* __restrict__ xz, const float* __restrict__ cw,
                      const float* __restrict__ cb, bf16_t* __restrict__ u) {
    int idx = blockIdx.x * 256 + threadIdx.x;      // over L_SEQ*DI/2
    if (idx >= L_SEQ * DI / 2) return;
    int chp = idx & (DI / 2 - 1);
    int l   = idx >> 10;
    int ch  = chp * 2;
    float acc0 = cb[ch], acc1 = cb[ch + 1];
    const float4* cwv = (const float4*)(cw + ch * 4);      // [ch][0..3]
    float4 c0 = cwv[0], c1 = cwv[1];
    float w0[4] = {c0.x, c0.y, c0.z, c0.w};
    float w1[4] = {c1.x, c1.y, c1.z, c1.w};
#pragma unroll
    for (int k = 0; k < 4; k++) {
        int ls = l - 3 + k;
        if (ls >= 0) {
            const bf16_t* p = xz + (size_t)ls * (2 * DI) + ch;
            acc0 += w0[k] * __bfloat162float(p[0]);
            acc1 += w1[k] * __bfloat162float(p[1]);
        }
    }
    float s0 = acc0 / (1.f + __expf(-acc0));
    float s1 = acc1 / (1.f + __expf(-acc1));
    bf16_t o0 = __float2bfloat16(s0), o1 = __float2bfloat16(s1);
    unsigned int packed = (unsigned int)*(unsigned short*)&o0 |
                          ((unsigned int)*(unsigned short*)&o1 << 16);
    *(unsigned int*)(u + (size_t)l * DI + ch) = packed;
}

// ---------------------------------------------------------------------------
// Selective scan pass 1 (lane-pair split): lanes l / l+32 share one channel d,
// each holds 8 of 16 states. 256 threads = 128 channels. Grid (NCHUNK, DI/128).
// Writes S (state from h=0) and dtsum[c][d] (P recomputed in pass2).
// ---------------------------------------------------------------------------
__global__ __launch_bounds__(256)
void scan_pass1(const bf16_t* __restrict__ dt, const bf16_t* __restrict__ u,
                const float* __restrict__ x_dbl, const float* __restrict__ A_log,
                float* __restrict__ dtsum, float* __restrict__ Sw) {
    int c = blockIdx.x;
    int tid = threadIdx.x;
    int lane = tid & 63, w = tid >> 6;
    int dloc = w * 32 + (lane & 31);
    int n0 = (lane >> 5) * 8;
    int d = blockIdx.y * 128 + dloc;
    int l0 = c * CHUNK;
    __shared__ float sB[CHUNK * NST];
    for (int i = tid; i < CHUNK * NST; i += 256)
        sB[i] = x_dbl[(size_t)(l0 + (i >> 4)) * XDBL_N + DTRANK + (i & 15)];
    __syncthreads();
    float Areg[8], h[8];
#pragma unroll
    for (int j = 0; j < 8; j++) {
        Areg[j] = -__expf(A_log[d * NST + n0 + j]);
        h[j] = 0.f;
    }
    float dts = 0.f;
    float dtl = __bfloat162float(dt[(size_t)l0 * DI + d]);
    float ul  = __bfloat162float(u[(size_t)l0 * DI + d]);
    for (int l = 0; l < CHUNK; l++) {
        float dtn = 0.f, un = 0.f;
        if (l + 1 < CHUNK) {
            int gl = l0 + l + 1;
            dtn = __bfloat162float(dt[(size_t)gl * DI + d]);
            un  = __bfloat162float(u[(size_t)gl * DI + d]);
        }
        float du = dtl * ul;
        dts += dtl;
#pragma unroll
        for (int j = 0; j < 8; j++) {
            float a = __expf(dtl * Areg[j]);
            h[j] = a * h[j] + du * sB[l * NST + n0 + j];
        }
        dtl = dtn; ul = un;
    }
    size_t base = ((size_t)c * DI + d) * NST + n0;
#pragma unroll
    for (int j = 0; j < 8; j++)
        Sw[base + j] = h[j];
    if (n0 == 0)
        dtsum[(size_t)c * DI + d] = dts;
}

// ---------------------------------------------------------------------------
// Selective scan pass 2: sequential prefix over chunks; init in-place over Sw.
// P recomputed from dtsum + A_log. thread tid = d*NST + n.
// ---------------------------------------------------------------------------
__global__ __launch_bounds__(256)
void scan_pass2(const float* __restrict__ dtsum, const float* __restrict__ A_log,
                float* __restrict__ SwInit) {
    int tid = blockIdx.x * 256 + threadIdx.x;   // 0 .. DI*NST-1
    if (tid >= DI * NST) return;
    int d = tid >> 4;
    float A = -__expf(A_log[tid]);              // A_log[d][n] flat = tid
    const int DN = DI * NST;
    size_t idx = tid;
    float h = 0.f;
    float ds = dtsum[d], s = SwInit[idx];
    for (int c = 0; c < NCHUNK; c++) {
        size_t nidx = idx + DN;
        float dsn = 0.f, sn = 0.f;
        if (c + 1 < NCHUNK) {
            dsn = dtsum[(size_t)(c + 1) * DI + d];
            sn  = SwInit[nidx];
        }
        float p = __expf(ds * A);
        SwInit[idx] = h;                 // becomes init state for chunk c
        h = p * h + s;
        ds = dsn; s = sn; idx = nidx;
    }
}

// ---------------------------------------------------------------------------
// Selective scan pass 3 (lane-pair split): replay with init,
// yy = (h.C + u*D) * silu(z); y halves combined via shfl_xor(32).
// ---------------------------------------------------------------------------
__global__ __launch_bounds__(256)
void scan_pass3(const bf16_t* __restrict__ dt, const bf16_t* __restrict__ u,
                const float* __restrict__ x_dbl, const float* __restrict__ A_log,
                const float* __restrict__ Dp, const float* __restrict__ initw,
                const bf16_t* __restrict__ xz, bf16_t* __restrict__ yy) {
    int c = blockIdx.x;
    int tid = threadIdx.x;
    int lane = tid & 63, w = tid >> 6;
    int dloc = w * 32 + (lane & 31);
    int n0 = (lane >> 5) * 8;
    int d = blockIdx.y * 128 + dloc;
    int l0 = c * CHUNK;
    __shared__ float sBC[CHUNK * 2 * NST];
    for (int i = tid; i < CHUNK * 2 * NST; i += 256)
        sBC[i] = x_dbl[(size_t)(l0 + (i >> 5)) * XDBL_N + DTRANK + (i & 31)];
    __syncthreads();
    float Areg[8], h[8];
    size_t base = ((size_t)c * DI + d) * NST + n0;
#pragma unroll
    for (int j = 0; j < 8; j++) {
        Areg[j] = -__expf(A_log[d * NST + n0 + j]);
        h[j] = initw[base + j];
    }
    float Dd = Dp[d];
    float dtl = __bfloat162float(dt[(size_t)l0 * DI + d]);
    float ul  = __bfloat162float(u[(size_t)l0 * DI + d]);
    float zv  = __bfloat162float(xz[(size_t)l0 * (2 * DI) + DI + d]);
    for (int l = 0; l < CHUNK; l++) {
        float dtn = 0.f, un = 0.f, zn = 0.f;
        if (l + 1 < CHUNK) {
            int gl = l0 + l + 1;
            dtn = __bfloat162float(dt[(size_t)gl * DI + d]);
            un  = __bfloat162float(u[(size_t)gl * DI + d]);
            zn  = __bfloat162float(xz[(size_t)gl * (2 * DI) + DI + d]);
        }
        float du = dtl * ul;
        float y = 0.f;
#pragma unroll
        for (int j = 0; j < 8; j++) {
            float a = __expf(dtl * Areg[j]);
            h[j] = a * h[j] + du * sBC[l * 32 + n0 + j];
            y += h[j] * sBC[l * 32 + NST + n0 + j];
        }
        y += __shfl_xor(y, 32);
        float sz = zv / (1.f + __expf(-zv));
        if ((lane >> 5) == 0)
            yy[(size_t)(l0 + l) * DI + d] = __float2bfloat16((y + ul * Dd) * sz);
        dtl = dtn; ul = un; zv = zn;
    }
}

// ---------------------------------------------------------------------------
extern "C" void kernel_launch(void* const* d_in, const int* in_sizes, int n_in,
                              void* d_out, int out_size, void* d_ws, size_t ws_size,
                              hipStream_t stream) {
    const float* vst        = (const float*)d_in[0];
    const float* ln_w       = (const float*)d_in[1];
    const float* ln_b       = (const float*)d_in[2];
    const float* in_proj_w  = (const float*)d_in[3];
    const float* conv_w     = (const float*)d_in[4];
    const float* conv_b     = (const float*)d_in[5];
    const float* x_proj_w   = (const float*)d_in[6];
    const float* dt_proj_w  = (const float*)d_in[7];
    const float* dt_proj_b  = (const float*)d_in[8];
    const float* A_log      = (const float*)d_in[9];
    const float* D_param    = (const float*)d_in[10];
    const float* out_proj_w = (const float*)d_in[11];
    const float* fln_w      = (const float*)d_in[12];
    const float* fln_b      = (const float*)d_in[13];
    const float* mlp_w1     = (const float*)d_in[14];
    const float* mlp_b1     = (const float*)d_in[15];
    const float* mlp_w2     = (const float*)d_in[16];
    const float* mlp_b2     = (const float*)d_in[17];
    float* out = (float*)d_out;

    // ---------------- workspace layout (byte-identical to round 9) ----------------
    char* wsb = (char*)d_ws;
    size_t off = 0;
    auto alloc_bf = [&](size_t n) { bf16_t* p = (bf16_t*)(wsb + off); off += n * 2; return p; };
    auto alloc_f  = [&](size_t n) { float*  p = (float*)(wsb + off); off += n * 4; return p; };

    // bf16 transposed weights (m2t slot retained; now hosts g6part)
    bf16_t* w1t  = alloc_bf((size_t)(2 * DI) * DMODEL);   // [4096,1024]
    bf16_t* xpt  = alloc_bf((size_t)128 * DI);            // [128,2048] (96 padded)
    bf16_t* dtpt = alloc_bf((size_t)DI * DTRANK);         // [2048,64]
    bf16_t* opt  = alloc_bf((size_t)DMODEL * DI);         // [1024,2048]
    bf16_t* m1t  = alloc_bf((size_t)HID * DMODEL);        // [4096,1024]
    bf16_t* m2t  = alloc_bf((size_t)HID * HID);           // [4096,4096] slot (unused as weights)
    // activations
    bf16_t* xz_bf   = alloc_bf((size_t)L_SEQ * 2 * DI);   // 33.5 MB
    bf16_t* u_bf    = alloc_bf((size_t)L_SEQ * DI);       // 16.8 MB
    bf16_t* dt_bf   = alloc_bf((size_t)L_SEQ * DI);       // 16.8 MB
    bf16_t* xdbl_bf = alloc_bf((size_t)L_SEQ * XDBL_N);
    bf16_t* yy_bf   = alloc_bf((size_t)L_SEQ * DI);       // 16.8 MB
    float*  xdbl_f  = alloc_f((size_t)L_SEQ * XDBL_N);
    float*  Pw      = alloc_f((size_t)NCHUNK * DI * NST); // 16.8 MB (g2part / dtsum)
    float*  Sw      = alloc_f((size_t)NCHUNK * DI * NST); // 16.8 MB (S + init, in-place)
    // aliases over dead regions
    bf16_t* xn_bf   = yy_bf;           // LN1 out; dead before pass3 writes yy
    float*  g2part  = Pw;              // [8][4096][128] fp32, dead before pass1
    float*  dtsum   = Pw;              // [128][2048] fp32 = 1 MB, written by pass1
    bf16_t* g4part  = xz_bf;           // [2][4096][1024] bf16, xz dead after pass3
    bf16_t* pooled  = dt_bf;           // dt dead after pass3
    bf16_t* h1_bf   = dt_bf + (size_t)POOLED_ROWS * DMODEL;
    float*  g5part  = (float*)yy_bf;   // [4][256][4096] fp32, yy dead after G4
    float*  g6part  = (float*)m2t;     // [8][256][4096] fp32 = 33.5 MB in m2t slot

    dim3 blk256(256);

    // 0) weight transposes (w2 excluded), one dispatch (1344 tiles)
    transpose_all_kernel<<<1344, blk256, 0, stream>>>(
        in_proj_w, w1t, x_proj_w, xpt, dt_proj_w, dtpt,
        out_proj_w, opt, mlp_w1, m1t);

    // 1) LN1: vst -> xn_bf
    ln_kernel<<<L_SEQ, blk256, 0, stream>>>(vst, ln_w, ln_b, xn_bf);

    // 2) G1: xz = xn @ in_proj  -> bf16 [L,4096]
    mfma_gemm<0><<<dim3((2 * DI) / 128, L_SEQ / 128), blk256, 0, stream>>>(
        xn_bf, DMODEL, w1t, DMODEL, DMODEL, nullptr, xz_bf, 2 * DI, nullptr, nullptr);

    // 3) conv+silu (channel-pair vectorized): xz[:,:DI] -> u_bf
    conv_silu_kernel<<<(L_SEQ * DI / 2) / 256, blk256, 0, stream>>>(xz_bf, conv_w, conv_b, u_bf);

    // 4) G2 split-K(8): x_dbl = u @ x_proj  [4096,2048]x[2048,96->128]
    mfma_gemm_splitk<false><<<dim3(1, L_SEQ / 128, 8), blk256, 0, stream>>>(
        u_bf, DI, xpt, DI, DI / 8, g2part, 128, (size_t)L_SEQ * 128);
    reduce_splitk<8, 0><<<(L_SEQ * XDBL_N) / 256, blk256, 0, stream>>>(
        g2part, (size_t)L_SEQ * 128, 128, L_SEQ, XDBL_N, xdbl_f, xdbl_bf, XDBL_N, nullptr);

    // 5) G3: dt = softplus(x_dbl[:,:64] @ dt_proj + b) -> bf16 [L,2048]
    mfma_gemm<1><<<dim3(DI / 128, L_SEQ / 128), blk256, 0, stream>>>(
        xdbl_bf, XDBL_N, dtpt, DTRANK, DTRANK, nullptr, dt_bf, DI, dt_proj_b, nullptr);

    // 6-8) chunked selective scan (CHUNK=32, lane-pair split: 32 waves/CU)
    scan_pass1<<<dim3(NCHUNK, DI / 128), blk256, 0, stream>>>(
        dt_bf, u_bf, xdbl_f, A_log, dtsum, Sw);
    scan_pass2<<<(DI * NST) / 256, blk256, 0, stream>>>(dtsum, A_log, Sw);
    scan_pass3<<<dim3(NCHUNK, DI / 128), blk256, 0, stream>>>(
        dt_bf, u_bf, xdbl_f, A_log, D_param, Sw, xz_bf, yy_bf);

    // 9) G4 split-K(2), bf16 partials: yy @ out_proj (residual folded into pool)
    mfma_gemm_splitk<true><<<dim3(DMODEL / 128, L_SEQ / 128, 2), blk256, 0, stream>>>(
        yy_bf, DI, opt, DI, DI / 2, g4part, DMODEL, (size_t)L_SEQ * DMODEL);

    // 10) fused G4-reduce + residual + LN2 + avgpool -> pooled bf16 [256,1024]
    ln_pool2_kernel<<<POOLED_ROWS, blk256, 0, stream>>>(
        g4part, (size_t)L_SEQ * DMODEL, vst, fln_w, fln_b, pooled);

    // 12) G5 split-K(4): h1 = gelu(pooled @ mlp_w1 + b1) -> bf16 [256,4096]
    mfma_gemm_splitk<false><<<dim3(HID / 128, POOLED_ROWS / 128, 4), blk256, 0, stream>>>(
        pooled, DMODEL, m1t, DMODEL, DMODEL / 4, g5part, HID, (size_t)POOLED_ROWS * HID);
    reduce_splitk<4, 1><<<(POOLED_ROWS * HID) / 256, blk256, 0, stream>>>(
        g5part, (size_t)POOLED_ROWS * HID, HID, POOLED_ROWS, HID, nullptr, h1_bf, HID, mlp_b1);

    // 13) G6: out = h1 @ mlp_w2(native fp32) + b2, NT kernel split-K(8)
    gemm_nt_kernel<<<dim3(HID / 64, 1, 8), dim3(512), 0, stream>>>(
        h1_bf, HID, mlp_w2, HID, HID / 8, g6part, HID, (size_t)POOLED_ROWS * HID);
    reduce_splitk<8, 2><<<(POOLED_ROWS * HID) / 256, blk256, 0, stream>>>(
        g6part, (size_t)POOLED_ROWS * HID, HID, POOLED_ROWS, HID, out, nullptr, HID, mlp_b2);
}

// Round 11
// 431.917 us; speedup vs baseline: 1.2507x; 1.0423x over previous
//
#include <hip/hip_runtime.h>
#include <hip/hip_bf16.h>
#include <math.h>

typedef __hip_bfloat16 bf16_t;
typedef __attribute__((ext_vector_type(8))) short short8;
typedef __attribute__((ext_vector_type(4))) float f32x4;

// Problem constants
#define L_SEQ   4096      // F*P = 16*256
#define DMODEL  1024
#define DI      2048
#define NST     16
#define DTRANK  64
#define XDBL_N  96        // DTRANK + 2*NST
#define HID     4096
#define CHUNK   32
#define NCHUNK  128       // L_SEQ / CHUNK
#define POOLED_ROWS 256   // 16 frames * 4 * 4

// ---------------------------------------------------------------------------
// async global->LDS 16B copy (global_load_lds_dwordx4)
// ---------------------------------------------------------------------------
__device__ __forceinline__ void async_load16(const bf16_t* g, bf16_t* l) {
    __builtin_amdgcn_global_load_lds(
        (const __attribute__((address_space(1))) void*)g,
        (__attribute__((address_space(3))) void*)l,
        16, 0, 0);
}
__device__ __forceinline__ void async_load16f(const float* g, float* l) {
    __builtin_amdgcn_global_load_lds(
        (const __attribute__((address_space(1))) void*)g,
        (__attribute__((address_space(3))) void*)l,
        16, 0, 0);
}

// branchless stable softplus with fast intrinsics (bf16-output accuracy)
__device__ __forceinline__ float softplus_f(float x) {
    return fmaxf(x, 0.f) + __logf(1.f + __expf(-fabsf(x)));
}

// ---------------------------------------------------------------------------
// Fused transpose+convert for 5 weights (w2 consumed natively by gemm_nt).
// 128k x 64n tiles. fp32 [K,N] row-major -> bf16 [Npad,K], pad rows zero.
//   j0 in_proj  K=1024 N=4096 Npad=4096: 512   [0,512)
//   j1 x_proj   K=2048 N=96   Npad=128 :  32   [512,544)
//   j2 dt_proj  K=64   N=2048 Npad=2048:  32   [544,576)
//   j3 out_proj K=2048 N=1024 Npad=1024: 256   [576,832)
//   j4 mlp_w1   K=1024 N=4096 Npad=4096: 512   [832,1344)
// ---------------------------------------------------------------------------
__global__ __launch_bounds__(256)
void transpose_all_kernel(const float* __restrict__ j0, bf16_t* __restrict__ o0,
                          const float* __restrict__ j1, bf16_t* __restrict__ o1,
                          const float* __restrict__ j2, bf16_t* __restrict__ o2,
                          const float* __restrict__ j3, bf16_t* __restrict__ o3,
                          const float* __restrict__ j4, bf16_t* __restrict__ o4) {
    int b = blockIdx.x;
    const float* in; bf16_t* out; int K, N, Npad, local;
    if (b < 512)        { in = j0; out = o0; K = 1024; N = 4096; Npad = 4096; local = b; }
    else if (b < 544)   { in = j1; out = o1; K = 2048; N = 96;   Npad = 128;  local = b - 512; }
    else if (b < 576)   { in = j2; out = o2; K = 64;   N = 2048; Npad = 2048; local = b - 544; }
    else if (b < 832)   { in = j3; out = o3; K = 2048; N = 1024; Npad = 1024; local = b - 576; }
    else                { in = j4; out = o4; K = 1024; N = 4096; Npad = 4096; local = b - 832; }
    int nt = Npad >> 6;
    int k0 = (local / nt) << 7, n0 = (local % nt) << 6;

    __shared__ float t[64 * 129];    // t[n][k], stride 129
    int tid = threadIdx.x;
    int kkb = tid >> 4;              // 0..15
    int nq  = (tid & 15) * 4;
#pragma unroll
    for (int it = 0; it < 8; it++) {
        int kl = it * 16 + kkb;      // 0..127
        int gk = k0 + kl, gn = n0 + nq;
        float4 v = {0.f, 0.f, 0.f, 0.f};
        if (gk < K) {
            const float* src = in + (size_t)gk * N + gn;
            if (gn + 3 < N) v = *(const float4*)src;
            else {
                if (gn + 0 < N) v.x = src[0];
                if (gn + 1 < N) v.y = src[1];
                if (gn + 2 < N) v.z = src[2];
                if (gn + 3 < N) v.w = src[3];
            }
        }
        t[(nq + 0) * 129 + kl] = v.x;
        t[(nq + 1) * 129 + kl] = v.y;
        t[(nq + 2) * 129 + kl] = v.z;
        t[(nq + 3) * 129 + kl] = v.w;
    }
    __syncthreads();
#pragma unroll
    for (int it = 0; it < 4; it++) {
        int slot = it * 256 + tid;
        int nn = slot >> 4, kc = (slot & 15) * 8;
        if (k0 + kc >= K) continue;
        const float* r = &t[nn * 129 + kc];
        short8 o;
#pragma unroll
        for (int j = 0; j < 8; j++) {
            bf16_t h = __float2bfloat16(r[j]);
            o[j] = *(short*)&h;
        }
        *(short8*)(out + (size_t)(n0 + nn) * K + k0 + kc) = o;
    }
}

// ---------------------------------------------------------------------------
// LayerNorm: one block per row, 1024 cols -> bf16
// ---------------------------------------------------------------------------
__global__ __launch_bounds__(256)
void ln_kernel(const float* __restrict__ x, const float* __restrict__ w,
               const float* __restrict__ b, bf16_t* __restrict__ out) {
    int row = blockIdx.x;
    int tid = threadIdx.x;
    const float* xr = x + (size_t)row * DMODEL;
    float v[4];
    float s = 0.f, ss = 0.f;
#pragma unroll
    for (int e = 0; e < 4; e++) {
        v[e] = xr[tid + e * 256];
        s += v[e];
        ss += v[e] * v[e];
    }
#pragma unroll
    for (int off = 32; off > 0; off >>= 1) {
        s  += __shfl_down(s, off);
        ss += __shfl_down(ss, off);
    }
    __shared__ float rs[4], rss[4];
    int wid = tid >> 6;
    if ((tid & 63) == 0) { rs[wid] = s; rss[wid] = ss; }
    __syncthreads();
    s  = rs[0] + rs[1] + rs[2] + rs[3];
    ss = rss[0] + rss[1] + rss[2] + rss[3];
    float mu  = s * (1.f / DMODEL);
    float var = ss * (1.f / DMODEL) - mu * mu;
    float inv = rsqrtf(var + 1e-5f);
#pragma unroll
    for (int e = 0; e < 4; e++) {
        int col = tid + e * 256;
        out[(size_t)row * DMODEL + col] =
            __float2bfloat16((v[e] - mu) * inv * w[col] + b[col]);
    }
}

// ---------------------------------------------------------------------------
// Fused G4-reduce + residual + LN2 + partial AvgPool, stage A.
// Block b = p*4 + ii: LN 4 source rows (jj=0..3) of pooled row p, accumulate,
// write fp32 partial [p*4+ii][1024].
// ---------------------------------------------------------------------------
__global__ __launch_bounds__(256)
void ln_pool_a_kernel(const bf16_t* __restrict__ part, size_t pstride,
                      const float* __restrict__ res, const float* __restrict__ w,
                      const float* __restrict__ b, float* __restrict__ pool_part) {
    int blk = blockIdx.x;                // 0..1023
    int p = blk >> 2, ii = blk & 3;
    int tid = threadIdx.x;
    int f = p >> 4, i4 = (p >> 2) & 3, j4 = p & 3;
    __shared__ float rs[4], rss[4];
    float acc[4] = {0.f, 0.f, 0.f, 0.f};
    float wv[4], bv[4];
#pragma unroll
    for (int e = 0; e < 4; e++) { wv[e] = w[tid + e * 256]; bv[e] = b[tid + e * 256]; }
    for (int jj = 0; jj < 4; jj++) {
        int row = f * 256 + (i4 * 4 + ii) * 16 + j4 * 4 + jj;
        size_t ro = (size_t)row * DMODEL;
        float v[4];
        float s = 0.f, ss = 0.f;
#pragma unroll
        for (int e = 0; e < 4; e++) {
            int col = tid + e * 256;
            float x = res[ro + col]
                    + __bfloat162float(part[ro + col])
                    + __bfloat162float(part[pstride + ro + col]);
            v[e] = x;
            s += x;
            ss += x * x;
        }
#pragma unroll
        for (int off = 32; off > 0; off >>= 1) {
            s  += __shfl_down(s, off);
            ss += __shfl_down(ss, off);
        }
        int wid = tid >> 6;
        if ((tid & 63) == 0) { rs[wid] = s; rss[wid] = ss; }
        __syncthreads();
        s  = rs[0] + rs[1] + rs[2] + rs[3];
        ss = rss[0] + rss[1] + rss[2] + rss[3];
        float mu  = s * (1.f / DMODEL);
        float var = ss * (1.f / DMODEL) - mu * mu;
        float inv = rsqrtf(var + 1e-5f);
#pragma unroll
        for (int e = 0; e < 4; e++)
            acc[e] += (v[e] - mu) * inv * wv[e] + bv[e];
        __syncthreads();
    }
#pragma unroll
    for (int e = 0; e < 4; e++)
        pool_part[(size_t)blk * DMODEL + tid + e * 256] = acc[e];
}

// ---------------------------------------------------------------------------
// AvgPool stage B: pooled[p][col] = bf16(sum_ii pool_part[p*4+ii][col] / 16)
// ---------------------------------------------------------------------------
__global__ __launch_bounds__(256)
void ln_pool_b_kernel(const float* __restrict__ pool_part, bf16_t* __restrict__ pooled) {
    int idx = blockIdx.x * 256 + threadIdx.x;   // over 256*1024
    if (idx >= POOLED_ROWS * DMODEL) return;
    int p = idx >> 10, col = idx & (DMODEL - 1);
    float s = pool_part[(size_t)(p * 4 + 0) * DMODEL + col]
            + pool_part[(size_t)(p * 4 + 1) * DMODEL + col]
            + pool_part[(size_t)(p * 4 + 2) * DMODEL + col]
            + pool_part[(size_t)(p * 4 + 3) * DMODEL + col];
    pooled[idx] = __float2bfloat16(s * (1.f / 16.f));
}

// ---------------------------------------------------------------------------
// bf16 MFMA GEMM: C[M,Nt] = epi(A[M,K] @ Bt[Nt,K]^T)
// 128x128 tile, BK=32, 256 threads (4 waves). EPI: 0 bf16; 1 bias+softplus bf16
// ---------------------------------------------------------------------------
template <int EPI>
__global__ __launch_bounds__(256, 2)
void mfma_gemm(const bf16_t* __restrict__ A, int lda,
               const bf16_t* __restrict__ Bt, int ldb,
               int K,
               float* __restrict__ Cf, bf16_t* __restrict__ Cb, int ldc,
               const float* __restrict__ bias, const float* __restrict__ res) {
    __shared__ bf16_t Asl[128 * 32];
    __shared__ bf16_t Bsl[128 * 32];
    const int tid = threadIdx.x;
    const int l = tid & 63, w = tid >> 6;
    const int m0 = blockIdx.y * 128, n0 = blockIdx.x * 128;
    const int wm = (w >> 1) * 64, wn = (w & 1) * 64;

    const int srow = tid >> 2;
    const int skc = (tid & 3) * 8;
    const bf16_t* Ag = A + (size_t)(m0 + srow) * lda + skc;
    const bf16_t* Bg = Bt + (size_t)(n0 + srow) * ldb + skc;
    bf16_t* As0 = Asl + (size_t)(w * 64) * 8;
    bf16_t* As1 = Asl + (size_t)(256 + w * 64) * 8;
    bf16_t* Bs0 = Bsl + (size_t)(w * 64) * 8;
    bf16_t* Bs1 = Bsl + (size_t)(256 + w * 64) * 8;

    f32x4 acc[4][4];
#pragma unroll
    for (int i = 0; i < 4; i++)
#pragma unroll
        for (int j = 0; j < 4; j++) acc[i][j] = (f32x4){0.f, 0.f, 0.f, 0.f};

    const short8* Asv = (const short8*)Asl;
    const short8* Bsv = (const short8*)Bsl;
    const int fr = l >> 4;
    const int fc = l & 15;

    for (int k0 = 0; k0 < K; k0 += 32) {
        __syncthreads();
        async_load16(Ag, As0);
        async_load16(Ag + (size_t)64 * lda, As1);
        async_load16(Bg, Bs0);
        async_load16(Bg + (size_t)64 * ldb, Bs1);
        Ag += 32; Bg += 32;
        __syncthreads();

        short8 a[4], b[4];
#pragma unroll
        for (int im = 0; im < 4; im++)
            a[im] = Asv[(wm + im * 16 + fc) * 4 + fr];
#pragma unroll
        for (int in = 0; in < 4; in++)
            b[in] = Bsv[(wn + in * 16 + fc) * 4 + fr];
#pragma unroll
        for (int im = 0; im < 4; im++)
#pragma unroll
            for (int in = 0; in < 4; in++)
                acc[im][in] = __builtin_amdgcn_mfma_f32_16x16x32_bf16(
                    a[im], b[in], acc[im][in], 0, 0, 0);
    }

#pragma unroll
    for (int im = 0; im < 4; im++) {
        int mbase = m0 + wm + im * 16 + fr * 4;
#pragma unroll
        for (int in = 0; in < 4; in++) {
            int n = n0 + wn + in * 16 + fc;
            float bv = (EPI == 1) ? bias[n] : 0.f;
#pragma unroll
            for (int v = 0; v < 4; v++) {
                float x = acc[im][in][v];
                size_t off = (size_t)(mbase + v) * ldc + n;
                if (EPI == 0) {
                    Cb[off] = __float2bfloat16(x);
                } else if (EPI == 1) {
                    Cb[off] = __float2bfloat16(softplus_f(x + bv));
                }
            }
        }
    }
}

// ---------------------------------------------------------------------------
// Split-K variant: grid.z = K-split; partials fp32 (PBF16=0) or bf16 (PBF16=1)
// ---------------------------------------------------------------------------
template <bool PBF16>
__global__ __launch_bounds__(256, 2)
void mfma_gemm_splitk(const bf16_t* __restrict__ A, int lda,
                      const bf16_t* __restrict__ Bt, int ldb,
                      int Kper, void* __restrict__ Cpart, int ldc,
                      size_t pstride) {
    __shared__ bf16_t Asl[128 * 32];
    __shared__ bf16_t Bsl[128 * 32];
    const int tid = threadIdx.x;
    const int l = tid & 63, w = tid >> 6;
    const int m0 = blockIdx.y * 128, n0 = blockIdx.x * 128;
    const int wm = (w >> 1) * 64, wn = (w & 1) * 64;
    const int kbase = blockIdx.z * Kper;

    const int srow = tid >> 2;
    const int skc = (tid & 3) * 8;
    const bf16_t* Ag = A + (size_t)(m0 + srow) * lda + kbase + skc;
    const bf16_t* Bg = Bt + (size_t)(n0 + srow) * ldb + kbase + skc;
    bf16_t* As0 = Asl + (size_t)(w * 64) * 8;
    bf16_t* As1 = Asl + (size_t)(256 + w * 64) * 8;
    bf16_t* Bs0 = Bsl + (size_t)(w * 64) * 8;
    bf16_t* Bs1 = Bsl + (size_t)(256 + w * 64) * 8;

    f32x4 acc[4][4];
#pragma unroll
    for (int i = 0; i < 4; i++)
#pragma unroll
        for (int j = 0; j < 4; j++) acc[i][j] = (f32x4){0.f, 0.f, 0.f, 0.f};

    const short8* Asv = (const short8*)Asl;
    const short8* Bsv = (const short8*)Bsl;
    const int fr = l >> 4;
    const int fc = l & 15;

    for (int k0 = 0; k0 < Kper; k0 += 32) {
        __syncthreads();
        async_load16(Ag, As0);
        async_load16(Ag + (size_t)64 * lda, As1);
        async_load16(Bg, Bs0);
        async_load16(Bg + (size_t)64 * ldb, Bs1);
        Ag += 32; Bg += 32;
        __syncthreads();

        short8 a[4], b[4];
#pragma unroll
        for (int im = 0; im < 4; im++)
            a[im] = Asv[(wm + im * 16 + fc) * 4 + fr];
#pragma unroll
        for (int in = 0; in < 4; in++)
            b[in] = Bsv[(wn + in * 16 + fc) * 4 + fr];
#pragma unroll
        for (int im = 0; im < 4; im++)
#pragma unroll
            for (int in = 0; in < 4; in++)
                acc[im][in] = __builtin_amdgcn_mfma_f32_16x16x32_bf16(
                    a[im], b[in], acc[im][in], 0, 0, 0);
    }

#pragma unroll
    for (int im = 0; im < 4; im++) {
        int mbase = m0 + wm + im * 16 + fr * 4;
#pragma unroll
        for (int in = 0; in < 4; in++) {
            int n = n0 + wn + in * 16 + fc;
#pragma unroll
            for (int v = 0; v < 4; v++) {
                size_t o = (size_t)(mbase + v) * ldc + n;
                if (PBF16)
                    ((bf16_t*)Cpart)[(size_t)blockIdx.z * pstride + o] =
                        __float2bfloat16(acc[im][in][v]);
                else
                    ((float*)Cpart)[(size_t)blockIdx.z * pstride + o] = acc[im][in][v];
            }
        }
    }
}

// ---------------------------------------------------------------------------
// NT GEMM with fused B-convert: C[256,N] = A[256,K]bf16 @ B[K,N]fp32.
// ---------------------------------------------------------------------------
__global__ __launch_bounds__(512, 1)
void gemm_nt_kernel(const bf16_t* __restrict__ A, int lda,
                    const float* __restrict__ B, int ldb,
                    int Kper, float* __restrict__ Cpart, int ldc,
                    size_t pstride) {
    __shared__ bf16_t Asl[256 * 32];   // [m][k] bf16
    __shared__ float  Bsl[32 * 64];    // [k][n] fp32
    const int tid = threadIdx.x;
    const int l = tid & 63, w = tid >> 6;        // w 0..7
    const int n0 = blockIdx.x * 64;
    const int kbase = blockIdx.z * Kper;
    const int wm = w * 32;

    const int a_row = tid >> 2, a_kc = (tid & 3) * 8;
    const bf16_t* Ag = A + (size_t)a_row * lda + kbase + a_kc;
    bf16_t* As0 = Asl + (size_t)(w * 64) * 8;
    bf16_t* As1 = Asl + (size_t)(512 + w * 64) * 8;
    const int b_row = tid >> 4, b_nc = (tid & 15) * 4;
    const float* Bg = B + (size_t)(kbase + b_row) * ldb + n0 + b_nc;
    float* Bs0 = Bsl + (size_t)(w * 64) * 4;

    f32x4 acc[2][4];
#pragma unroll
    for (int i = 0; i < 2; i++)
#pragma unroll
        for (int j = 0; j < 4; j++) acc[i][j] = (f32x4){0.f, 0.f, 0.f, 0.f};

    const short8* Asv = (const short8*)Asl;
    const int fr = l >> 4, fc = l & 15;

    for (int k0 = 0; k0 < Kper; k0 += 32) {
        __syncthreads();
        async_load16(Ag, As0);
        async_load16(Ag + (size_t)128 * lda, As1);
        async_load16f(Bg, Bs0);
        Ag += 32;
        Bg += (size_t)32 * ldb;
        __syncthreads();

        short8 a[2], bfr[4];
        a[0] = Asv[(wm + fc) * 4 + fr];
        a[1] = Asv[(wm + 16 + fc) * 4 + fr];
#pragma unroll
        for (int j = 0; j < 4; j++) {
            const float* bp = Bsl + (size_t)(fr * 8) * 64 + j * 16 + fc;
            short8 t;
#pragma unroll
            for (int i = 0; i < 8; i++) {
                bf16_t h = __float2bfloat16(bp[i * 64]);
                t[i] = *(short*)&h;
            }
            bfr[j] = t;
        }
#pragma unroll
        for (int im = 0; im < 2; im++)
#pragma unroll
            for (int j = 0; j < 4; j++)
                acc[im][j] = __builtin_amdgcn_mfma_f32_16x16x32_bf16(
                    a[im], bfr[j], acc[im][j], 0, 0, 0);
    }

    float* Cz = Cpart + (size_t)blockIdx.z * pstride;
#pragma unroll
    for (int im = 0; im < 2; im++) {
        int mbase = wm + im * 16 + fr * 4;
#pragma unroll
        for (int j = 0; j < 4; j++) {
            int n = n0 + j * 16 + fc;
#pragma unroll
            for (int v = 0; v < 4; v++)
                Cz[(size_t)(mbase + v) * ldc + n] = acc[im][j][v];
        }
    }
}

// ---------------------------------------------------------------------------
// Split-K reduce, float4-vectorized (4 consecutive cols / thread).
// EPI: 0 fp32+bf16; 1 bias+gelu bf16; 2 bias fp32.  N % 4 == 0.
// ---------------------------------------------------------------------------
template <int S, int EPI>
__global__ __launch_bounds__(256)
void reduce_splitk4(const float* __restrict__ part, size_t pstride, int ldp,
                    int M, int N, float* __restrict__ outf, bf16_t* __restrict__ outb,
                    int ldo, const float* __restrict__ bias) {
    int idx = blockIdx.x * 256 + threadIdx.x;
    int npr = N >> 2;
    if (idx >= M * npr) return;
    int r = idx / npr, c = (idx - r * npr) << 2;
    f32x4 s = (f32x4){0.f, 0.f, 0.f, 0.f};
#pragma unroll
    for (int z = 0; z < S; z++)
        s += *(const f32x4*)(part + (size_t)z * pstride + (size_t)r * ldp + c);
    size_t o = (size_t)r * ldo + c;
    if (EPI == 0) {
        *(f32x4*)(outf + o) = s;
        short8 pk;  // only low 4 used via ushort4 store
        ushort4 ub;
#pragma unroll
        for (int e = 0; e < 4; e++) {
            bf16_t h = __float2bfloat16(s[e]);
            ((unsigned short*)&ub)[e] = *(unsigned short*)&h;
        }
        *(ushort4*)(outb + o) = ub;
        (void)pk;
    } else if (EPI == 1) {
        f32x4 bv = *(const f32x4*)(bias + c);
        ushort4 ub;
#pragma unroll
        for (int e = 0; e < 4; e++) {
            float x = s[e] + bv[e];
            x = 0.5f * x * (1.f + erff(x * 0.70710678118654752f));
            bf16_t h = __float2bfloat16(x);
            ((unsigned short*)&ub)[e] = *(unsigned short*)&h;
        }
        *(ushort4*)(outb + o) = ub;
    } else {
        f32x4 bv = *(const f32x4*)(bias + c);
        *(f32x4*)(outf + o) = s + bv;
    }
}

// ---------------------------------------------------------------------------
// Depthwise causal conv (k=4) + bias + silu, channel-pair vectorized.
// ---------------------------------------------------------------------------
__global__ __launch_bounds__(256)
void conv_silu_kernel(const bf16_t* __restrict__ xz, const float* __restrict__ cw,
                      const float* __restrict__ cb, bf16_t* __restrict__ u) {
    int idx = blockIdx.x * 256 + threadIdx.x;      // over L_SEQ*DI/2
    if (idx >= L_SEQ * DI / 2) return;
    int chp = idx & (DI / 2 - 1);
    int l   = idx >> 10;
    int ch  = chp * 2;
    float acc0 = cb[ch], acc1 = cb[ch + 1];
    const float4* cwv = (const float4*)(cw + ch * 4);      // [ch][0..3]
    float4 c0 = cwv[0], c1 = cwv[1];
    float w0[4] = {c0.x, c0.y, c0.z, c0.w};
    float w1[4] = {c1.x, c1.y, c1.z, c1.w};
#pragma unroll
    for (int k = 0; k < 4; k++) {
        int ls = l - 3 + k;
        if (ls >= 0) {
            const bf16_t* p = xz + (size_t)ls * (2 * DI) + ch;
            acc0 += w0[k] * __bfloat162float(p[0]);
            acc1 += w1[k] * __bfloat162float(p[1]);
        }
    }
    float s0 = acc0 / (1.f + __expf(-acc0));
    float s1 = acc1 / (1.f + __expf(-acc1));
    bf16_t o0 = __float2bfloat16(s0), o1 = __float2bfloat16(s1);
    unsigned int packed = (unsigned int)*(unsigned short*)&o0 |
                          ((unsigned int)*(unsigned short*)&o1 << 16);
    *(unsigned int*)(u + (size_t)l * DI + ch) = packed;
}

// ---------------------------------------------------------------------------
// Selective scan pass 1 (lane-pair split): lanes l / l+32 share one channel d,
// each holds 8 of 16 states. 256 threads = 128 channels. Grid (NCHUNK, DI/128).
// Writes S (state from h=0) and dtsum[c][d] (P recomputed in pass2).
// ---------------------------------------------------------------------------
__global__ __launch_bounds__(256)
void scan_pass1(const bf16_t* __restrict__ dt, const bf16_t* __restrict__ u,
                const float* __restrict__ x_dbl, const float* __restrict__ A_log,
                float* __restrict__ dtsum, float* __restrict__ Sw) {
    int c = blockIdx.x;
    int tid = threadIdx.x;
    int lane = tid & 63, w = tid >> 6;
    int dloc = w * 32 + (lane & 31);
    int n0 = (lane >> 5) * 8;
    int d = blockIdx.y * 128 + dloc;
    int l0 = c * CHUNK;
    __shared__ float sB[CHUNK * NST];
    for (int i = tid; i < CHUNK * NST; i += 256)
        sB[i] = x_dbl[(size_t)(l0 + (i >> 4)) * XDBL_N + DTRANK + (i & 15)];
    __syncthreads();
    float Areg[8], h[8];
#pragma unroll
    for (int j = 0; j < 8; j++) {
        Areg[j] = -__expf(A_log[d * NST + n0 + j]);
        h[j] = 0.f;
    }
    float dts = 0.f;
    float dtl = __bfloat162float(dt[(size_t)l0 * DI + d]);
    float ul  = __bfloat162float(u[(size_t)l0 * DI + d]);
    for (int l = 0; l < CHUNK; l++) {
        float dtn = 0.f, un = 0.f;
        if (l + 1 < CHUNK) {
            int gl = l0 + l + 1;
            dtn = __bfloat162float(dt[(size_t)gl * DI + d]);
            un  = __bfloat162float(u[(size_t)gl * DI + d]);
        }
        float du = dtl * ul;
        dts += dtl;
#pragma unroll
        for (int j = 0; j < 8; j++) {
            float a = __expf(dtl * Areg[j]);
            h[j] = a * h[j] + du * sB[l * NST + n0 + j];
        }
        dtl = dtn; ul = un;
    }
    size_t base = ((size_t)c * DI + d) * NST + n0;
#pragma unroll
    for (int j = 0; j < 8; j++)
        Sw[base + j] = h[j];
    if (n0 == 0)
        dtsum[(size_t)c * DI + d] = dts;
}

// ---------------------------------------------------------------------------
// Selective scan pass 2: sequential prefix over chunks; init in-place over Sw.
// 8-chunk batched loads to hide latency. P recomputed from dtsum + A_log.
// ---------------------------------------------------------------------------
__global__ __launch_bounds__(256)
void scan_pass2(const float* __restrict__ dtsum, const float* __restrict__ A_log,
                float* __restrict__ SwInit) {
    int tid = blockIdx.x * 256 + threadIdx.x;   // 0 .. DI*NST-1
    if (tid >= DI * NST) return;
    int d = tid >> 4;
    float A = -__expf(A_log[tid]);
    const size_t DN = DI * NST;
    float h = 0.f;
    for (int c = 0; c < NCHUNK; c += 8) {
        float ds8[8], s8[8];
#pragma unroll
        for (int j = 0; j < 8; j++) {
            ds8[j] = dtsum[(size_t)(c + j) * DI + d];
            s8[j]  = SwInit[(size_t)(c + j) * DN + tid];
        }
#pragma unroll
        for (int j = 0; j < 8; j++) {
            float p = __expf(ds8[j] * A);
            SwInit[(size_t)(c + j) * DN + tid] = h;
            h = p * h + s8[j];
        }
    }
}

// ---------------------------------------------------------------------------
// Selective scan pass 3 (lane-pair split): replay with init,
// yy = (h.C + u*D) * silu(z); y halves combined via shfl_xor(32).
// ---------------------------------------------------------------------------
__global__ __launch_bounds__(256)
void scan_pass3(const bf16_t* __restrict__ dt, const bf16_t* __restrict__ u,
                const float* __restrict__ x_dbl, const float* __restrict__ A_log,
                const float* __restrict__ Dp, const float* __restrict__ initw,
                const bf16_t* __restrict__ xz, bf16_t* __restrict__ yy) {
    int c = blockIdx.x;
    int tid = threadIdx.x;
    int lane = tid & 63, w = tid >> 6;
    int dloc = w * 32 + (lane & 31);
    int n0 = (lane >> 5) * 8;
    int d = blockIdx.y * 128 + dloc;
    int l0 = c * CHUNK;
    __shared__ float sBC[CHUNK * 2 * NST];
    for (int i = tid; i < CHUNK * 2 * NST; i += 256)
        sBC[i] = x_dbl[(size_t)(l0 + (i >> 5)) * XDBL_N + DTRANK + (i & 31)];
    __syncthreads();
    float Areg[8], h[8];
    size_t base = ((size_t)c * DI + d) * NST + n0;
#pragma unroll
    for (int j = 0; j < 8; j++) {
        Areg[j] = -__expf(A_log[d * NST + n0 + j]);
        h[j] = initw[base + j];
    }
    float Dd = Dp[d];
    float dtl = __bfloat162float(dt[(size_t)l0 * DI + d]);
    float ul  = __bfloat162float(u[(size_t)l0 * DI + d]);
    float zv  = __bfloat162float(xz[(size_t)l0 * (2 * DI) + DI + d]);
    for (int l = 0; l < CHUNK; l++) {
        float dtn = 0.f, un = 0.f, zn = 0.f;
        if (l + 1 < CHUNK) {
            int gl = l0 + l + 1;
            dtn = __bfloat162float(dt[(size_t)gl * DI + d]);
            un  = __bfloat162float(u[(size_t)gl * DI + d]);
            zn  = __bfloat162float(xz[(size_t)gl * (2 * DI) + DI + d]);
        }
        float du = dtl * ul;
        float y = 0.f;
#pragma unroll
        for (int j = 0; j < 8; j++) {
            float a = __expf(dtl * Areg[j]);
            h[j] = a * h[j] + du * sBC[l * 32 + n0 + j];
            y += h[j] * sBC[l * 32 + NST + n0 + j];
        }
        y += __shfl_xor(y, 32);
        float sz = zv / (1.f + __expf(-zv));
        if ((lane >> 5) == 0)
            yy[(size_t)(l0 + l) * DI + d] = __float2bfloat16((y + ul * Dd) * sz);
        dtl = dtn; ul = un; zv = zn;
    }
}

// ---------------------------------------------------------------------------
extern "C" void kernel_launch(void* const* d_in, const int* in_sizes, int n_in,
                              void* d_out, int out_size, void* d_ws, size_t ws_size,
                              hipStream_t stream) {
    const float* vst        = (const float*)d_in[0];
    const float* ln_w       = (const float*)d_in[1];
    const float* ln_b       = (const float*)d_in[2];
    const float* in_proj_w  = (const float*)d_in[3];
    const float* conv_w     = (const float*)d_in[4];
    const float* conv_b     = (const float*)d_in[5];
    const float* x_proj_w   = (const float*)d_in[6];
    const float* dt_proj_w  = (const float*)d_in[7];
    const float* dt_proj_b  = (const float*)d_in[8];
    const float* A_log      = (const float*)d_in[9];
    const float* D_param    = (const float*)d_in[10];
    const float* out_proj_w = (const float*)d_in[11];
    const float* fln_w      = (const float*)d_in[12];
    const float* fln_b      = (const float*)d_in[13];
    const float* mlp_w1     = (const float*)d_in[14];
    const float* mlp_b1     = (const float*)d_in[15];
    const float* mlp_w2     = (const float*)d_in[16];
    const float* mlp_b2     = (const float*)d_in[17];
    float* out = (float*)d_out;

    // ---------------- workspace layout (identical to round 10) ----------------
    char* wsb = (char*)d_ws;
    size_t off = 0;
    auto alloc_bf = [&](size_t n) { bf16_t* p = (bf16_t*)(wsb + off); off += n * 2; return p; };
    auto alloc_f  = [&](size_t n) { float*  p = (float*)(wsb + off); off += n * 4; return p; };

    bf16_t* w1t  = alloc_bf((size_t)(2 * DI) * DMODEL);   // [4096,1024]
    bf16_t* xpt  = alloc_bf((size_t)128 * DI);            // [128,2048] (96 padded)
    bf16_t* dtpt = alloc_bf((size_t)DI * DTRANK);         // [2048,64]
    bf16_t* opt  = alloc_bf((size_t)DMODEL * DI);         // [1024,2048]
    bf16_t* m1t  = alloc_bf((size_t)HID * DMODEL);        // [4096,1024]
    bf16_t* m2t  = alloc_bf((size_t)HID * HID);           // [4096,4096] slot -> g6part
    bf16_t* xz_bf   = alloc_bf((size_t)L_SEQ * 2 * DI);   // 33.5 MB
    bf16_t* u_bf    = alloc_bf((size_t)L_SEQ * DI);       // 16.8 MB
    bf16_t* dt_bf   = alloc_bf((size_t)L_SEQ * DI);       // 16.8 MB
    bf16_t* xdbl_bf = alloc_bf((size_t)L_SEQ * XDBL_N);
    bf16_t* yy_bf   = alloc_bf((size_t)L_SEQ * DI);       // 16.8 MB
    float*  xdbl_f  = alloc_f((size_t)L_SEQ * XDBL_N);
    float*  Pw      = alloc_f((size_t)NCHUNK * DI * NST); // (g2part / dtsum)
    float*  Sw      = alloc_f((size_t)NCHUNK * DI * NST); // (S + init, in-place)
    // aliases over dead regions
    bf16_t* xn_bf   = yy_bf;           // LN1 out; dead before pass3 writes yy
    float*  g2part  = Pw;              // dead before pass1
    float*  dtsum   = Pw;              // [128][2048] fp32, written by pass1
    bf16_t* g4part  = xz_bf;           // [2][4096][1024] bf16, xz dead after pass3
    bf16_t* pooled  = dt_bf;           // dt dead after pass3
    bf16_t* h1_bf   = dt_bf + (size_t)POOLED_ROWS * DMODEL;
    float*  pool_part = (float*)yy_bf; // [1024][1024] fp32 = 4.2 MB, yy dead after G4
    float*  g5part  = (float*)yy_bf;   // [4][256][4096] fp32 (after pool stage B)
    float*  g6part  = (float*)m2t;     // [8][256][4096] fp32 in m2t slot

    dim3 blk256(256);

    // 0) weight transposes (w2 excluded), one dispatch (1344 tiles)
    transpose_all_kernel<<<1344, blk256, 0, stream>>>(
        in_proj_w, w1t, x_proj_w, xpt, dt_proj_w, dtpt,
        out_proj_w, opt, mlp_w1, m1t);

    // 1) LN1: vst -> xn_bf
    ln_kernel<<<L_SEQ, blk256, 0, stream>>>(vst, ln_w, ln_b, xn_bf);

    // 2) G1: xz = xn @ in_proj  -> bf16 [L,4096]
    mfma_gemm<0><<<dim3((2 * DI) / 128, L_SEQ / 128), blk256, 0, stream>>>(
        xn_bf, DMODEL, w1t, DMODEL, DMODEL, nullptr, xz_bf, 2 * DI, nullptr, nullptr);

    // 3) conv+silu (channel-pair vectorized): xz[:,:DI] -> u_bf
    conv_silu_kernel<<<(L_SEQ * DI / 2) / 256, blk256, 0, stream>>>(xz_bf, conv_w, conv_b, u_bf);

    // 4) G2 split-K(8): x_dbl = u @ x_proj  [4096,2048]x[2048,96->128]
    mfma_gemm_splitk<false><<<dim3(1, L_SEQ / 128, 8), blk256, 0, stream>>>(
        u_bf, DI, xpt, DI, DI / 8, g2part, 128, (size_t)L_SEQ * 128);
    reduce_splitk4<8, 0><<<(L_SEQ * (XDBL_N / 4) + 255) / 256, blk256, 0, stream>>>(
        g2part, (size_t)L_SEQ * 128, 128, L_SEQ, XDBL_N, xdbl_f, xdbl_bf, XDBL_N, nullptr);

    // 5) G3: dt = softplus(x_dbl[:,:64] @ dt_proj + b) -> bf16 [L,2048]
    mfma_gemm<1><<<dim3(DI / 128, L_SEQ / 128), blk256, 0, stream>>>(
        xdbl_bf, XDBL_N, dtpt, DTRANK, DTRANK, nullptr, dt_bf, DI, dt_proj_b, nullptr);

    // 6-8) chunked selective scan (CHUNK=32, lane-pair split: 32 waves/CU)
    scan_pass1<<<dim3(NCHUNK, DI / 128), blk256, 0, stream>>>(
        dt_bf, u_bf, xdbl_f, A_log, dtsum, Sw);
    scan_pass2<<<(DI * NST) / 256, blk256, 0, stream>>>(dtsum, A_log, Sw);
    scan_pass3<<<dim3(NCHUNK, DI / 128), blk256, 0, stream>>>(
        dt_bf, u_bf, xdbl_f, A_log, D_param, Sw, xz_bf, yy_bf);

    // 9) G4 split-K(2), bf16 partials: yy @ out_proj (residual folded into pool)
    mfma_gemm_splitk<true><<<dim3(DMODEL / 128, L_SEQ / 128, 2), blk256, 0, stream>>>(
        yy_bf, DI, opt, DI, DI / 2, g4part, DMODEL, (size_t)L_SEQ * DMODEL);

    // 10) fused G4-reduce + residual + LN2 + avgpool, two-stage
    ln_pool_a_kernel<<<1024, blk256, 0, stream>>>(
        g4part, (size_t)L_SEQ * DMODEL, vst, fln_w, fln_b, pool_part);
    ln_pool_b_kernel<<<(POOLED_ROWS * DMODEL) / 256, blk256, 0, stream>>>(
        pool_part, pooled);

    // 12) G5 split-K(4): h1 = gelu(pooled @ mlp_w1 + b1) -> bf16 [256,4096]
    mfma_gemm_splitk<false><<<dim3(HID / 128, POOLED_ROWS / 128, 4), blk256, 0, stream>>>(
        pooled, DMODEL, m1t, DMODEL, DMODEL / 4, g5part, HID, (size_t)POOLED_ROWS * HID);
    reduce_splitk4<4, 1><<<(POOLED_ROWS * (HID / 4)) / 256, blk256, 0, stream>>>(
        g5part, (size_t)POOLED_ROWS * HID, HID, POOLED_ROWS, HID, nullptr, h1_bf, HID, mlp_b1);

    // 13) G6: out = h1 @ mlp_w2(native fp32) + b2, NT kernel split-K(8)
    gemm_nt_kernel<<<dim3(HID / 64, 1, 8), dim3(512), 0, stream>>>(
        h1_bf, HID, mlp_w2, HID, HID / 8, g6part, HID, (size_t)POOLED_ROWS * HID);
    reduce_splitk4<8, 2><<<(POOLED_ROWS * (HID / 4)) / 256, blk256, 0, stream>>>(
        g6part, (size_t)POOLED_ROWS * HID, HID, POOLED_ROWS, HID, out, nullptr, HID, mlp_b2);
}